// Round 4
// baseline (3775.384 us; speedup 1.0000x reference)
//
#include <hip/hip_runtime.h>
#include <stdint.h>

// Problem constants
#define BB   128      // batch
#define LL   128      // latent dim
#define HH   1024     // hidden
#define G4   4096     // 4*H
#define TT   256      // time steps
#define PP   128      // output cols per step

#define NGB  64                  // gate blocks: each owns 16 hidden units (64 weight rows)
#define NFB  8                   // fc blocks: each owns 16 rows of W_fc
#define NB   (NGB + NFB)

typedef _Float16 half8  __attribute__((ext_vector_type(8)));
typedef float   floatx4 __attribute__((ext_vector_type(4)));

__device__ __forceinline__ float sigf(float x) {
  x = fminf(fmaxf(x, -30.f), 30.f);
  return 1.f / (1.f + __expf(-x));
}
__device__ __forceinline__ float tanhf_fast(float x) {
  x = fminf(fmaxf(x, -15.f), 15.f);
  float e = __expf(2.f * x);
  return (e - 1.f) / (e + 1.f);
}
__device__ __forceinline__ unsigned short f2h(float x) {
  _Float16 h = (_Float16)x;
  return __builtin_bit_cast(unsigned short, h);
}
// agent-scope write-through h store: at LLC once vmcnt(0) drains
__device__ __forceinline__ void store_h(unsigned short* p, float x) {
  __hip_atomic_store(p, f2h(x), __ATOMIC_RELAXED, __HIP_MEMORY_SCOPE_AGENT);
}

// LLC-coherent 16B load: sc0 sc1 -> bypass L1/L2, read at the coherence point
// (where the write-through h stores land). Hand-pipelined with counted vmcnt.
#define ALOAD(dst, base, IMM)                                              \
  asm volatile("global_load_dwordx4 %0, %1, off offset:%2 sc0 sc1"         \
               : "=&v"(dst) : "v"(base), "n"(IMM) : "memory")

// One pipeline stage: wait for pair kc (counted), 2*NT MFMAs, reissue slot.
// 16-pair ring => 32 loads in flight per wave (r3's 8-pair ring paced the
// gemm at L/8; measured step time implies LLC latency ~3-5k cyc, so depth 16
// halves the pacing). The "+v" ties make the MFMAs data-depend on the wait
// (rule #18: MFMA would otherwise hoist past an inline-asm waitcnt).
#define KSTEP(kc, WN)                                                      \
  {                                                                        \
    asm volatile("s_waitcnt vmcnt(%2)"                                     \
                 : "+v"(ap0[(kc) & 15]), "+v"(ap1[(kc) & 15]) : "n"(WN));  \
    half8 a0 = ap0[(kc) & 15], a1 = ap1[(kc) & 15];                        \
    const int sw = ((kc) * 4 + quad) ^ rsw;                                \
    _Pragma("unroll")                                                      \
    for (int nt = 0; nt < NT; ++nt) {                                      \
      half8 b = w8[(nt * 16 + l15) * 128 + sw];                            \
      acc[0][nt] = __builtin_amdgcn_mfma_f32_16x16x32_f16(a0, b, acc[0][nt], 0, 0, 0); \
      acc[1][nt] = __builtin_amdgcn_mfma_f32_16x16x32_f16(a1, b, acc[1][nt], 0, 0, 0); \
    }                                                                      \
    if ((kc) < 16) {                                                       \
      ALOAD(ap0[(kc) & 15], p0, ((kc) + 16) * 64);                         \
      ALOAD(ap1[(kc) & 15], p1, ((kc) + 16) * 64);                         \
    }                                                                      \
  }

// Flat monotonic per-step grid barrier, zero cache-maintenance ops.
// Release: h stores are write-through agent-scope, drained (vmcnt(0)) before
// the one syncthreads that gates the arrival add. Acquire: not needed — all
// cross-step reads use sc0sc1 loads that read at the coherence point.
// NO trailing syncthreads: every wave polls the counter itself and starts
// its A-load stream the moment it observes the flag (one less sync hop on
// the per-step serial chain).
__device__ __forceinline__ void stepbar(unsigned* bar, unsigned target) {
  asm volatile("s_waitcnt vmcnt(0)" ::: "memory");   // own h stores at LLC
  __syncthreads();                                   // all waves drained
  if (threadIdx.x == 0)
    __hip_atomic_fetch_add(bar, 1u, __ATOMIC_RELAXED, __HIP_MEMORY_SCOPE_AGENT);
  while (__hip_atomic_load(bar, __ATOMIC_RELAXED, __HIP_MEMORY_SCOPE_AGENT) < target)
    __builtin_amdgcn_s_sleep(1);
}

// gates0 = z @ w_ih^T + b_ih + b_hh   (step-0 gates; h0=c0=0, x=0 for t>=1)
__global__ void prep_gates0(const float* __restrict__ z, const float* __restrict__ w_ih,
                            const float* __restrict__ b_ih, const float* __restrict__ b_hh,
                            float* __restrict__ g0) {
  int j = blockIdx.x;     // 0..4095
  int b = threadIdx.x;    // 0..127
  const float* zr = z + b * LL;
  const float* wr = w_ih + (size_t)j * LL;
  float s = 0.f;
#pragma unroll 4
  for (int k = 0; k < LL; ++k) s += zr[k] * wr[k];
  g0[(size_t)b * G4 + j] = s + b_ih[j] + b_hh[j];
}

// Convert w_hh / W_fc to fp16 in the persistent kernel's LDS layout.
// Gate block bid owns units u = bid*16 .. bid*16+15; LDS rows (tile*16+nl) for
// tile 0..3 = gates i,g,f,o of unit nl. Each row's 8-elem k-chunks are
// XOR-swizzled by (nl&7) so the wave's B-reads are same-bank-free.
__global__ void prep_weights(const float* __restrict__ w_hh, const float* __restrict__ W_fc,
                             unsigned short* __restrict__ wbuf) {
  int R = blockIdx.x;                 // 0..4223 (4096 gate rows + 128 fc rows)
  const float* src; int rsw;
  if (R < NGB * 64) {
    int bid = R >> 6, rr = R & 63, tile = rr >> 4, nl = rr & 15;
    int g = (tile == 0) ? 0 : (tile == 1) ? 2 : (tile == 2) ? 1 : 3;  // i,g,f,o
    src = w_hh + (size_t)(g * HH + bid * 16 + nl) * HH;
    rsw = nl & 7;
  } else {
    int p = R - NGB * 64;
    src = W_fc + (size_t)p * HH;
    rsw = p & 7;
  }
  unsigned short* dst = wbuf + (size_t)R * HH;
  for (int k = threadIdx.x; k < HH; k += blockDim.x) {
    int dk = (((k >> 3) ^ rsw) << 3) | (k & 7);
    _Float16 v = (_Float16)src[k];
    dst[dk] = __builtin_bit_cast(unsigned short, v);
  }
}

// One K=1024 MFMA pass: C[2 mtiles x NT ntiles]. A streamed from global h via
// sc0sc1 16B loads (LLC-coherent), hand-pipelined 16-deep per m-stream with
// counted vmcnt. B from LDS (fp16, swizzled).
template <int NT>
__device__ __forceinline__ void gemm2xNT(const unsigned short* __restrict__ hb,
                                         const half8* __restrict__ w8,
                                         int au0, int au1,   // ushort units
                                         int quad, int rsw, int l15,
                                         floatx4 acc[2][NT]) {
  const unsigned short* p0 = hb + au0;
  const unsigned short* p1 = hb + au1;
  half8 ap0[16], ap1[16];
  ALOAD(ap0[0],  p0, 0);    ALOAD(ap1[0],  p1, 0);
  ALOAD(ap0[1],  p0, 64);   ALOAD(ap1[1],  p1, 64);
  ALOAD(ap0[2],  p0, 128);  ALOAD(ap1[2],  p1, 128);
  ALOAD(ap0[3],  p0, 192);  ALOAD(ap1[3],  p1, 192);
  ALOAD(ap0[4],  p0, 256);  ALOAD(ap1[4],  p1, 256);
  ALOAD(ap0[5],  p0, 320);  ALOAD(ap1[5],  p1, 320);
  ALOAD(ap0[6],  p0, 384);  ALOAD(ap1[6],  p1, 384);
  ALOAD(ap0[7],  p0, 448);  ALOAD(ap1[7],  p1, 448);
  ALOAD(ap0[8],  p0, 512);  ALOAD(ap1[8],  p1, 512);
  ALOAD(ap0[9],  p0, 576);  ALOAD(ap1[9],  p1, 576);
  ALOAD(ap0[10], p0, 640);  ALOAD(ap1[10], p1, 640);
  ALOAD(ap0[11], p0, 704);  ALOAD(ap1[11], p1, 704);
  ALOAD(ap0[12], p0, 768);  ALOAD(ap1[12], p1, 768);
  ALOAD(ap0[13], p0, 832);  ALOAD(ap1[13], p1, 832);
  ALOAD(ap0[14], p0, 896);  ALOAD(ap1[14], p1, 896);
  ALOAD(ap0[15], p0, 960);  ALOAD(ap1[15], p1, 960);
  KSTEP(0, 30)  KSTEP(1, 30)  KSTEP(2, 30)  KSTEP(3, 30)
  KSTEP(4, 30)  KSTEP(5, 30)  KSTEP(6, 30)  KSTEP(7, 30)
  KSTEP(8, 30)  KSTEP(9, 30)  KSTEP(10, 30) KSTEP(11, 30)
  KSTEP(12, 30) KSTEP(13, 30) KSTEP(14, 30) KSTEP(15, 30)
  KSTEP(16, 30) KSTEP(17, 28) KSTEP(18, 26) KSTEP(19, 24)
  KSTEP(20, 22) KSTEP(21, 20) KSTEP(22, 18) KSTEP(23, 16)
  KSTEP(24, 14) KSTEP(25, 12) KSTEP(26, 10) KSTEP(27, 8)
  KSTEP(28, 6)  KSTEP(29, 4)  KSTEP(30, 2)  KSTEP(31, 0)
}

__global__ __launch_bounds__(256, 1) void lstm_persist(
    const float* __restrict__ g0,
    const unsigned short* __restrict__ wbuf,
    const float* __restrict__ b_ih, const float* __restrict__ b_hh,
    const float* __restrict__ b_fc,
    float* __restrict__ out,
    unsigned short* __restrict__ hbuf,   // [2][B][H] fp16 double buffer
    unsigned* __restrict__ ctl) {        // monotonic barrier counter at ctl+64
  extern __shared__ __align__(16) unsigned short sW[];
  const int tid  = threadIdx.x;
  const int wv   = tid >> 6;
  const int lane = tid & 63;
  const int quad = lane >> 4;
  const int l15  = lane & 15;
  const int bid  = blockIdx.x;
  const bool isg = bid < NGB;
  const int rsw  = l15 & 7;

  unsigned* bar = ctl + 64;          // single flat monotonic counter

  { // stage this block's weight slice into LDS (already fp16 + swizzled in wbuf)
    const uint4* s4 = (const uint4*)(wbuf +
        (size_t)(isg ? bid * 64 : NGB * 64 + (bid - NGB) * 16) * HH);
    uint4* d4 = (uint4*)sW;
    const int n16 = (isg ? 64 * HH : 16 * HH) / 8;
    for (int i = tid; i < n16; i += 256) d4[i] = s4[i];
  }
  __syncthreads();
  const half8* w8 = (const half8*)sW;
  const floatx4 z4 = {0.f, 0.f, 0.f, 0.f};

  if (isg) {
    const int u = bid * 16 + l15;   // hidden unit this lane owns (all 4 gates)
    const float bi = b_ih[u]          + b_hh[u];
    const float bf = b_ih[HH + u]     + b_hh[HH + u];
    const float bg = b_ih[2*HH + u]   + b_hh[2*HH + u];
    const float bo = b_ih[3*HH + u]   + b_hh[3*HH + u];
    float c[2][4] = {{0,0,0,0},{0,0,0,0}};

    // ---- t = 0: gates precomputed in g0; c_prev = 0
#pragma unroll
    for (int mt = 0; mt < 2; ++mt)
#pragma unroll
      for (int r = 0; r < 4; ++r) {
        const int m = wv * 32 + mt * 16 + quad * 4 + r;
        const float* gr = g0 + (size_t)m * G4;
        float iv = gr[u], gv = gr[2 * HH + u], ov = gr[3 * HH + u];
        float ct = sigf(iv) * tanhf_fast(gv);
        c[mt][r] = ct;
        store_h(hbuf + (size_t)m * HH + u, sigf(ov) * tanhf_fast(ct));
      }
    stepbar(bar, NB);   // publish h(0)

    const int au0 = (wv * 32 +      l15) * 1024 + quad * 8;  // ushort units
    const int au1 = (wv * 32 + 16 + l15) * 1024 + quad * 8;

    for (int t = 1; t < TT; ++t) {
      const unsigned short* hb = hbuf + (size_t)((t - 1) & 1) * BB * HH;
      unsigned short* hw = hbuf + (size_t)(t & 1) * BB * HH;
      floatx4 acc[2][4] = {{z4, z4, z4, z4}, {z4, z4, z4, z4}};
      gemm2xNT<4>(hb, w8, au0, au1, quad, rsw, l15, acc);
#pragma unroll
      for (int mt = 0; mt < 2; ++mt)
#pragma unroll
        for (int r = 0; r < 4; ++r) {
          float iv = sigf(acc[mt][0][r] + bi);
          float gv = tanhf_fast(acc[mt][1][r] + bg);
          float fv = sigf(acc[mt][2][r] + bf);
          float ov = sigf(acc[mt][3][r] + bo);
          float ct = fv * c[mt][r] + iv * gv;
          c[mt][r] = ct;
          const int m = wv * 32 + mt * 16 + quad * 4 + r;
          store_h(hw + (size_t)m * HH + u, ov * tanhf_fast(ct));
        }
      stepbar(bar, NB * (unsigned)(t + 1));
    }
  } else {
    // fc block: y_{t-1} = h_{t-1} @ W_fc^T + b_fc, overlapped with step-t gate GEMMs
    const int fb = bid - NGB;
    const int pcol = fb * 16 + l15;
    const float biasf = b_fc[pcol];
    const int au0 = ((wv * 2 + 0) * 16 + l15) * 1024 + quad * 8;  // ushort units
    const int au1 = ((wv * 2 + 1) * 16 + l15) * 1024 + quad * 8;

    stepbar(bar, NB);   // t = 0: nothing to project yet; wait for h(0)

    for (int t = 1; t <= TT; ++t) {
      const unsigned short* hb = hbuf + (size_t)((t - 1) & 1) * BB * HH;
      floatx4 acc[2][1] = {{z4}, {z4}};
      gemm2xNT<1>(hb, w8, au0, au1, quad, rsw, l15, acc);
#pragma unroll
      for (int mt = 0; mt < 2; ++mt)
#pragma unroll
        for (int r = 0; r < 4; ++r) {
          const int m = (wv * 2 + mt) * 16 + quad * 4 + r;
          out[(size_t)m * (TT * PP) + (size_t)(t - 1) * PP + pcol] = acc[mt][0][r] + biasf;
        }
      if (t < TT) stepbar(bar, NB * (unsigned)(t + 1));
    }
  }
}

extern "C" void kernel_launch(void* const* d_in, const int* in_sizes, int n_in,
                              void* d_out, int out_size, void* d_ws, size_t ws_size,
                              hipStream_t stream) {
  const float* z    = (const float*)d_in[1];
  const float* w_ih = (const float*)d_in[2];
  const float* w_hh = (const float*)d_in[3];
  const float* b_ih = (const float*)d_in[4];
  const float* b_hh = (const float*)d_in[5];
  const float* W_fc = (const float*)d_in[6];
  const float* b_fc = (const float*)d_in[7];
  float* out = (float*)d_out;

  // workspace layout (~10.8 MiB total)
  char* ws = (char*)d_ws;
  unsigned*       ctl  = (unsigned*)ws;                                        // 4 KiB ctrl
  unsigned short* hbuf = (unsigned short*)(ws + 4096);                         // 512 KiB
  float*          g0   = (float*)(ws + 4096 + (size_t)2 * BB * HH * 2);        // 2 MiB
  unsigned short* wbuf = (unsigned short*)(ws + 4096 + (size_t)2 * BB * HH * 2
                                              + (size_t)BB * G4 * 4);          // 8.25 MiB

  // allow 128 KiB dynamic LDS (gfx950 has 160 KiB/CU)
  (void)hipFuncSetAttribute(reinterpret_cast<const void*>(lstm_persist),
                            hipFuncAttributeMaxDynamicSharedMemorySize, 160 * 1024);

  hipMemsetAsync(ctl, 0, 4096, stream);
  prep_gates0 <<<dim3(G4), dim3(BB), 0, stream>>>(z, w_ih, b_ih, b_hh, g0);
  prep_weights<<<dim3(NGB * 64 + NFB * 16), dim3(256), 0, stream>>>(w_hh, W_fc, wbuf);
  lstm_persist<<<dim3(NB), dim3(256), 128 * 1024, stream>>>(g0, wbuf, b_ih, b_hh, b_fc,
                                                            out, hbuf, ctl);
}

// Round 5
// 3130.070 us; speedup vs baseline: 1.2062x; 1.2062x over previous
//
#include <hip/hip_runtime.h>
#include <stdint.h>

// Problem constants
#define BB   128      // batch
#define LL   128      // latent dim
#define HH   1024     // hidden
#define G4   4096     // 4*H
#define TT   256      // time steps
#define PP   128      // output cols per step

#define NGB  64                  // gate blocks: each owns 16 hidden units (64 weight rows)
#define NFB  8                   // fc blocks: each owns 16 rows of W_fc
#define NB   (NGB + NFB)

// h rows are stored DUPLICATED: row stride 2048 ushorts, [1024..2047] mirrors
// [0..1023]. This lets each wave start its K-sweep at an arbitrary chunk
// offset koff (column stagger) while keeping compile-time load offsets
// (a 32-chunk run from koff never wraps: max byte offset 31*64+31*64 < 4096).
#define HROW 2048

typedef _Float16 half8  __attribute__((ext_vector_type(8)));
typedef float   floatx4 __attribute__((ext_vector_type(4)));

__device__ __forceinline__ float sigf(float x) {
  x = fminf(fmaxf(x, -30.f), 30.f);
  return 1.f / (1.f + __expf(-x));
}
__device__ __forceinline__ float tanhf_fast(float x) {
  x = fminf(fmaxf(x, -15.f), 15.f);
  float e = __expf(2.f * x);
  return (e - 1.f) / (e + 1.f);
}
__device__ __forceinline__ unsigned short f2h(float x) {
  _Float16 h = (_Float16)x;
  return __builtin_bit_cast(unsigned short, h);
}
// agent-scope write-through h store: at LLC once vmcnt(0) drains
__device__ __forceinline__ void store_h(unsigned short* p, float x) {
  __hip_atomic_store(p, f2h(x), __ATOMIC_RELAXED, __HIP_MEMORY_SCOPE_AGENT);
}

// LLC-coherent 16B load: sc0 sc1 -> read at the coherence point.
#define ALOAD(dst, base, IMM)                                              \
  asm volatile("global_load_dwordx4 %0, %1, off offset:%2 sc0 sc1"         \
               : "=&v"(dst) : "v"(base), "n"(IMM) : "memory")

// One pipeline stage: wait for pair kc (counted), 2*NT MFMAs, reissue slot.
// kc is the LOGICAL sweep index; the physical k-chunk is (kc+koff)&31 —
// per-wave column stagger so the 288 waves don't sweep the LLC in lockstep
// (herd dispersal: identical-order sweeps serialize on one LLC channel).
// The "+v" ties make the MFMAs data-depend on the wait (rule #18).
#define KSTEP(kc, WN)                                                      \
  {                                                                        \
    asm volatile("s_waitcnt vmcnt(%2)"                                     \
                 : "+v"(ap0[(kc) & 7]), "+v"(ap1[(kc) & 7]) : "n"(WN));    \
    half8 a0 = ap0[(kc) & 7], a1 = ap1[(kc) & 7];                          \
    const int kp = ((kc) + koff) & 31;                                     \
    const int sw = (kp * 4 + quad) ^ rsw;                                  \
    _Pragma("unroll")                                                      \
    for (int nt = 0; nt < NT; ++nt) {                                      \
      half8 b = w8[(nt * 16 + l15) * 128 + sw];                            \
      acc[0][nt] = __builtin_amdgcn_mfma_f32_16x16x32_f16(a0, b, acc[0][nt], 0, 0, 0); \
      acc[1][nt] = __builtin_amdgcn_mfma_f32_16x16x32_f16(a1, b, acc[1][nt], 0, 0, 0); \
    }                                                                      \
    if ((kc) < 24) {                                                       \
      ALOAD(ap0[(kc) & 7], p0, ((kc) + 8) * 64);                           \
      ALOAD(ap1[(kc) & 7], p1, ((kc) + 8) * 64);                           \
    }                                                                      \
  }

// Flat monotonic per-step grid barrier (r3 shape: thread-0 poll, trailing
// syncthreads), zero cache-maintenance ops.
__device__ __forceinline__ void stepbar(unsigned* bar, unsigned target) {
  __syncthreads();
  if (threadIdx.x == 0) {
    asm volatile("s_waitcnt vmcnt(0)" ::: "memory");   // h stores at LLC
    __hip_atomic_fetch_add(bar, 1u, __ATOMIC_RELAXED, __HIP_MEMORY_SCOPE_AGENT);
    while (__hip_atomic_load(bar, __ATOMIC_RELAXED, __HIP_MEMORY_SCOPE_AGENT) < target)
      __builtin_amdgcn_s_sleep(1);
  }
  __syncthreads();
}

// gates0 = z @ w_ih^T + b_ih + b_hh   (step-0 gates; h0=c0=0, x=0 for t>=1)
__global__ void prep_gates0(const float* __restrict__ z, const float* __restrict__ w_ih,
                            const float* __restrict__ b_ih, const float* __restrict__ b_hh,
                            float* __restrict__ g0) {
  int j = blockIdx.x;     // 0..4095
  int b = threadIdx.x;    // 0..127
  const float* zr = z + b * LL;
  const float* wr = w_ih + (size_t)j * LL;
  float s = 0.f;
#pragma unroll 4
  for (int k = 0; k < LL; ++k) s += zr[k] * wr[k];
  g0[(size_t)b * G4 + j] = s + b_ih[j] + b_hh[j];
}

// Convert w_hh / W_fc to fp16 in the persistent kernel's LDS layout.
// Gate block bid owns units u = bid*16 .. bid*16+15; LDS rows (tile*16+nl) for
// tile 0..3 = gates i,g,f,o of unit nl. Each row's 8-elem k-chunks are
// XOR-swizzled by (nl&7) so the wave's B-reads are same-bank-free.
__global__ void prep_weights(const float* __restrict__ w_hh, const float* __restrict__ W_fc,
                             unsigned short* __restrict__ wbuf) {
  int R = blockIdx.x;                 // 0..4223 (4096 gate rows + 128 fc rows)
  const float* src; int rsw;
  if (R < NGB * 64) {
    int bid = R >> 6, rr = R & 63, tile = rr >> 4, nl = rr & 15;
    int g = (tile == 0) ? 0 : (tile == 1) ? 2 : (tile == 2) ? 1 : 3;  // i,g,f,o
    src = w_hh + (size_t)(g * HH + bid * 16 + nl) * HH;
    rsw = nl & 7;
  } else {
    int p = R - NGB * 64;
    src = W_fc + (size_t)p * HH;
    rsw = p & 7;
  }
  unsigned short* dst = wbuf + (size_t)R * HH;
  for (int k = threadIdx.x; k < HH; k += blockDim.x) {
    int dk = (((k >> 3) ^ rsw) << 3) | (k & 7);
    _Float16 v = (_Float16)src[k];
    dst[dk] = __builtin_bit_cast(unsigned short, v);
  }
}

// One K=1024 MFMA pass: C[2 mtiles x NT ntiles]. A streamed from global h via
// sc0sc1 16B loads, hand-pipelined 8-deep per m-stream with counted vmcnt,
// column-staggered by koff. B from LDS (fp16, swizzled).
template <int NT>
__device__ __forceinline__ void gemm2xNT(const unsigned short* __restrict__ hb,
                                         const half8* __restrict__ w8,
                                         int au0, int au1,   // ushort units (incl. koff)
                                         int quad, int rsw, int l15, int koff,
                                         floatx4 acc[2][NT]) {
  const unsigned short* p0 = hb + au0;
  const unsigned short* p1 = hb + au1;
  half8 ap0[8], ap1[8];
  ALOAD(ap0[0], p0, 0);   ALOAD(ap1[0], p1, 0);
  ALOAD(ap0[1], p0, 64);  ALOAD(ap1[1], p1, 64);
  ALOAD(ap0[2], p0, 128); ALOAD(ap1[2], p1, 128);
  ALOAD(ap0[3], p0, 192); ALOAD(ap1[3], p1, 192);
  ALOAD(ap0[4], p0, 256); ALOAD(ap1[4], p1, 256);
  ALOAD(ap0[5], p0, 320); ALOAD(ap1[5], p1, 320);
  ALOAD(ap0[6], p0, 384); ALOAD(ap1[6], p1, 384);
  ALOAD(ap0[7], p0, 448); ALOAD(ap1[7], p1, 448);
  KSTEP(0, 14)  KSTEP(1, 14)  KSTEP(2, 14)  KSTEP(3, 14)
  KSTEP(4, 14)  KSTEP(5, 14)  KSTEP(6, 14)  KSTEP(7, 14)
  KSTEP(8, 14)  KSTEP(9, 14)  KSTEP(10, 14) KSTEP(11, 14)
  KSTEP(12, 14) KSTEP(13, 14) KSTEP(14, 14) KSTEP(15, 14)
  KSTEP(16, 14) KSTEP(17, 14) KSTEP(18, 14) KSTEP(19, 14)
  KSTEP(20, 14) KSTEP(21, 14) KSTEP(22, 14) KSTEP(23, 14)
  KSTEP(24, 14) KSTEP(25, 12) KSTEP(26, 10) KSTEP(27, 8)
  KSTEP(28, 6)  KSTEP(29, 4)  KSTEP(30, 2)  KSTEP(31, 0)
}

__global__ __launch_bounds__(256, 1) void lstm_persist(
    const float* __restrict__ g0,
    const unsigned short* __restrict__ wbuf,
    const float* __restrict__ b_ih, const float* __restrict__ b_hh,
    const float* __restrict__ b_fc,
    float* __restrict__ out,
    unsigned short* __restrict__ hbuf,   // [2][B][HROW] fp16, rows duplicated
    unsigned* __restrict__ ctl) {        // monotonic barrier counter at ctl+64
  extern __shared__ __align__(16) unsigned short sW[];
  const int tid  = threadIdx.x;
  const int wv   = tid >> 6;
  const int lane = tid & 63;
  const int quad = lane >> 4;
  const int l15  = lane & 15;
  const int bid  = blockIdx.x;
  const bool isg = bid < NGB;
  const int rsw  = l15 & 7;
  // per-wave column stagger: spread the 288 waves' K-sweeps over 32 chunks
  const int koff = ((bid * 4 + wv) * 13) & 31;

  unsigned* bar = ctl + 64;          // single flat monotonic counter

  { // stage this block's weight slice into LDS (already fp16 + swizzled in wbuf)
    const uint4* s4 = (const uint4*)(wbuf +
        (size_t)(isg ? bid * 64 : NGB * 64 + (bid - NGB) * 16) * HH);
    uint4* d4 = (uint4*)sW;
    const int n16 = (isg ? 64 * HH : 16 * HH) / 8;
    for (int i = tid; i < n16; i += 256) d4[i] = s4[i];
  }
  __syncthreads();
  const half8* w8 = (const half8*)sW;
  const floatx4 z4 = {0.f, 0.f, 0.f, 0.f};

  if (isg) {
    const int u = bid * 16 + l15;   // hidden unit this lane owns (all 4 gates)
    const float bi = b_ih[u]          + b_hh[u];
    const float bf = b_ih[HH + u]     + b_hh[HH + u];
    const float bg = b_ih[2*HH + u]   + b_hh[2*HH + u];
    const float bo = b_ih[3*HH + u]   + b_hh[3*HH + u];
    float c[2][4] = {{0,0,0,0},{0,0,0,0}};

    // ---- t = 0: gates precomputed in g0; c_prev = 0
#pragma unroll
    for (int mt = 0; mt < 2; ++mt)
#pragma unroll
      for (int r = 0; r < 4; ++r) {
        const int m = wv * 32 + mt * 16 + quad * 4 + r;
        const float* gr = g0 + (size_t)m * G4;
        float iv = gr[u], gv = gr[2 * HH + u], ov = gr[3 * HH + u];
        float ct = sigf(iv) * tanhf_fast(gv);
        c[mt][r] = ct;
        float hv = sigf(ov) * tanhf_fast(ct);
        store_h(hbuf + (size_t)m * HROW + u, hv);
        store_h(hbuf + (size_t)m * HROW + HH + u, hv);   // duplicate
      }
    stepbar(bar, NB);   // publish h(0)

    const int au0 = (wv * 32 +      l15) * HROW + koff * 32 + quad * 8;  // ushort units
    const int au1 = (wv * 32 + 16 + l15) * HROW + koff * 32 + quad * 8;

    for (int t = 1; t < TT; ++t) {
      const unsigned short* hb = hbuf + (size_t)((t - 1) & 1) * BB * HROW;
      unsigned short* hw = hbuf + (size_t)(t & 1) * BB * HROW;
      floatx4 acc[2][4] = {{z4, z4, z4, z4}, {z4, z4, z4, z4}};
      gemm2xNT<4>(hb, w8, au0, au1, quad, rsw, l15, koff, acc);
#pragma unroll
      for (int mt = 0; mt < 2; ++mt)
#pragma unroll
        for (int r = 0; r < 4; ++r) {
          float iv = sigf(acc[mt][0][r] + bi);
          float gv = tanhf_fast(acc[mt][1][r] + bg);
          float fv = sigf(acc[mt][2][r] + bf);
          float ov = sigf(acc[mt][3][r] + bo);
          float ct = fv * c[mt][r] + iv * gv;
          c[mt][r] = ct;
          const int m = wv * 32 + mt * 16 + quad * 4 + r;
          float hv = ov * tanhf_fast(ct);
          store_h(hw + (size_t)m * HROW + u, hv);
          store_h(hw + (size_t)m * HROW + HH + u, hv);   // duplicate
        }
      stepbar(bar, NB * (unsigned)(t + 1));
    }
  } else {
    // fc block: y_{t-1} = h_{t-1} @ W_fc^T + b_fc, overlapped with step-t gate GEMMs
    const int fb = bid - NGB;
    const int pcol = fb * 16 + l15;
    const float biasf = b_fc[pcol];
    const int au0 = ((wv * 2 + 0) * 16 + l15) * HROW + koff * 32 + quad * 8;
    const int au1 = ((wv * 2 + 1) * 16 + l15) * HROW + koff * 32 + quad * 8;

    stepbar(bar, NB);   // t = 0: nothing to project yet; wait for h(0)

    for (int t = 1; t <= TT; ++t) {
      const unsigned short* hb = hbuf + (size_t)((t - 1) & 1) * BB * HROW;
      floatx4 acc[2][1] = {{z4}, {z4}};
      gemm2xNT<1>(hb, w8, au0, au1, quad, rsw, l15, koff, acc);
#pragma unroll
      for (int mt = 0; mt < 2; ++mt)
#pragma unroll
        for (int r = 0; r < 4; ++r) {
          const int m = (wv * 2 + mt) * 16 + quad * 4 + r;
          out[(size_t)m * (TT * PP) + (size_t)(t - 1) * PP + pcol] = acc[mt][0][r] + biasf;
        }
      if (t < TT) stepbar(bar, NB * (unsigned)(t + 1));
    }
  }
}

extern "C" void kernel_launch(void* const* d_in, const int* in_sizes, int n_in,
                              void* d_out, int out_size, void* d_ws, size_t ws_size,
                              hipStream_t stream) {
  const float* z    = (const float*)d_in[1];
  const float* w_ih = (const float*)d_in[2];
  const float* w_hh = (const float*)d_in[3];
  const float* b_ih = (const float*)d_in[4];
  const float* b_hh = (const float*)d_in[5];
  const float* W_fc = (const float*)d_in[6];
  const float* b_fc = (const float*)d_in[7];
  float* out = (float*)d_out;

  // workspace layout (~11.3 MiB total)
  char* ws = (char*)d_ws;
  unsigned*       ctl  = (unsigned*)ws;                                        // 4 KiB ctrl
  unsigned short* hbuf = (unsigned short*)(ws + 4096);                         // 1 MiB (dup rows)
  float*          g0   = (float*)(ws + 4096 + (size_t)2 * BB * HROW * 2);      // 2 MiB
  unsigned short* wbuf = (unsigned short*)(ws + 4096 + (size_t)2 * BB * HROW * 2
                                              + (size_t)BB * G4 * 4);          // 8.25 MiB

  // allow 128 KiB dynamic LDS (gfx950 has 160 KiB/CU)
  (void)hipFuncSetAttribute(reinterpret_cast<const void*>(lstm_persist),
                            hipFuncAttributeMaxDynamicSharedMemorySize, 160 * 1024);

  hipMemsetAsync(ctl, 0, 4096, stream);
  prep_gates0 <<<dim3(G4), dim3(BB), 0, stream>>>(z, w_ih, b_ih, b_hh, g0);
  prep_weights<<<dim3(NGB * 64 + NFB * 16), dim3(256), 0, stream>>>(w_hh, W_fc, wbuf);
  lstm_persist<<<dim3(NB), dim3(256), 128 * 1024, stream>>>(g0, wbuf, b_ih, b_hh, b_fc,
                                                            out, hbuf, ctl);
}

// Round 6
// 2573.029 us; speedup vs baseline: 1.4673x; 1.2165x over previous
//
#include <hip/hip_runtime.h>
#include <stdint.h>

// Problem constants
#define BB   128      // batch
#define LL   128      // latent dim
#define HH   1024     // hidden
#define G4   4096     // 4*H
#define TT   256      // time steps
#define PP   128      // output cols per step

// 144 blocks x 128 threads (2 waves). Gate blocks: 64 weight-slices x 2
// batch-halves; fc blocks: 8 col-groups x 2 batch-halves. vs r3 (72 blocks
// x 4 waves, m=128/block): per-CU A-traffic and LDS-read load halve, chip
// CU usage doubles. Weight slice per gate block = 128 KiB LDS (forces one
// gate block per CU -> guaranteed spread across 128+ CUs).
#define NSL  64                  // weight slices (16 hidden units each)
#define NGB  128                 // gate blocks = NSL * 2 batch-halves
#define NFB  16                  // fc blocks = 8 col-groups * 2 batch-halves
#define NB   (NGB + NFB)

typedef _Float16 half8  __attribute__((ext_vector_type(8)));
typedef float   floatx4 __attribute__((ext_vector_type(4)));

__device__ __forceinline__ float sigf(float x) {
  x = fminf(fmaxf(x, -30.f), 30.f);
  return 1.f / (1.f + __expf(-x));
}
__device__ __forceinline__ float tanhf_fast(float x) {
  x = fminf(fmaxf(x, -15.f), 15.f);
  float e = __expf(2.f * x);
  return (e - 1.f) / (e + 1.f);
}
__device__ __forceinline__ unsigned short f2h(float x) {
  _Float16 h = (_Float16)x;
  return __builtin_bit_cast(unsigned short, h);
}
// agent-scope write-through h store: at LLC once vmcnt(0) drains
__device__ __forceinline__ void store_h(unsigned short* p, float x) {
  __hip_atomic_store(p, f2h(x), __ATOMIC_RELAXED, __HIP_MEMORY_SCOPE_AGENT);
}

// LLC-coherent 16B load: sc0 sc1 -> read at the coherence point.
#define ALOAD(dst, base, IMM)                                              \
  asm volatile("global_load_dwordx4 %0, %1, off offset:%2 sc0 sc1"         \
               : "=&v"(dst) : "v"(base), "n"(IMM) : "memory")

// One pipeline stage: wait for pair kc (counted), 2*NT MFMAs, reissue slot.
// The "+v" ties make the MFMAs data-depend on the wait (rule #18).
#define KSTEP(kc, WN)                                                      \
  {                                                                        \
    asm volatile("s_waitcnt vmcnt(%2)"                                     \
                 : "+v"(ap0[(kc) & 7]), "+v"(ap1[(kc) & 7]) : "n"(WN));    \
    half8 a0 = ap0[(kc) & 7], a1 = ap1[(kc) & 7];                          \
    const int sw = ((kc) * 4 + quad) ^ rsw;                                \
    _Pragma("unroll")                                                      \
    for (int nt = 0; nt < NT; ++nt) {                                      \
      half8 b = w8[(nt * 16 + l15) * 128 + sw];                            \
      acc[0][nt] = __builtin_amdgcn_mfma_f32_16x16x32_f16(a0, b, acc[0][nt], 0, 0, 0); \
      acc[1][nt] = __builtin_amdgcn_mfma_f32_16x16x32_f16(a1, b, acc[1][nt], 0, 0, 0); \
    }                                                                      \
    if ((kc) < 24) {                                                       \
      ALOAD(ap0[(kc) & 7], p0, ((kc) + 8) * 64);                           \
      ALOAD(ap1[(kc) & 7], p1, ((kc) + 8) * 64);                           \
    }                                                                      \
  }

// Flat monotonic per-step grid barrier (r3 shape), zero cache-maintenance.
__device__ __forceinline__ void stepbar(unsigned* bar, unsigned target) {
  __syncthreads();
  if (threadIdx.x == 0) {
    asm volatile("s_waitcnt vmcnt(0)" ::: "memory");   // h stores at LLC
    __hip_atomic_fetch_add(bar, 1u, __ATOMIC_RELAXED, __HIP_MEMORY_SCOPE_AGENT);
    while (__hip_atomic_load(bar, __ATOMIC_RELAXED, __HIP_MEMORY_SCOPE_AGENT) < target)
      __builtin_amdgcn_s_sleep(1);
  }
  __syncthreads();
}

// gates0 = z @ w_ih^T + b_ih + b_hh   (step-0 gates; h0=c0=0, x=0 for t>=1)
__global__ void prep_gates0(const float* __restrict__ z, const float* __restrict__ w_ih,
                            const float* __restrict__ b_ih, const float* __restrict__ b_hh,
                            float* __restrict__ g0) {
  int j = blockIdx.x;     // 0..4095
  int b = threadIdx.x;    // 0..127
  const float* zr = z + b * LL;
  const float* wr = w_ih + (size_t)j * LL;
  float s = 0.f;
#pragma unroll 4
  for (int k = 0; k < LL; ++k) s += zr[k] * wr[k];
  g0[(size_t)b * G4 + j] = s + b_ih[j] + b_hh[j];
}

// Convert w_hh / W_fc to fp16 in the persistent kernel's LDS layout.
// Weight slice sl owns units u = sl*16 .. sl*16+15; LDS rows (tile*16+nl) for
// tile 0..3 = gates i,g,f,o of unit nl. Each row's 8-elem k-chunks are
// XOR-swizzled by (nl&7) so the wave's B-reads are same-bank-free.
__global__ void prep_weights(const float* __restrict__ w_hh, const float* __restrict__ W_fc,
                             unsigned short* __restrict__ wbuf) {
  int R = blockIdx.x;                 // 0..4223 (4096 gate rows + 128 fc rows)
  const float* src; int rsw;
  if (R < NSL * 64) {
    int sl = R >> 6, rr = R & 63, tile = rr >> 4, nl = rr & 15;
    int g = (tile == 0) ? 0 : (tile == 1) ? 2 : (tile == 2) ? 1 : 3;  // i,g,f,o
    src = w_hh + (size_t)(g * HH + sl * 16 + nl) * HH;
    rsw = nl & 7;
  } else {
    int p = R - NSL * 64;
    src = W_fc + (size_t)p * HH;
    rsw = p & 7;
  }
  unsigned short* dst = wbuf + (size_t)R * HH;
  for (int k = threadIdx.x; k < HH; k += blockDim.x) {
    int dk = (((k >> 3) ^ rsw) << 3) | (k & 7);
    _Float16 v = (_Float16)src[k];
    dst[dk] = __builtin_bit_cast(unsigned short, v);
  }
}

// One K=1024 MFMA pass: C[2 mtiles x NT ntiles]. A streamed from global h via
// sc0sc1 16B loads, hand-pipelined 8-deep per m-stream with counted vmcnt.
// B from LDS (fp16, swizzled).
template <int NT>
__device__ __forceinline__ void gemm2xNT(const unsigned short* __restrict__ hb,
                                         const half8* __restrict__ w8,
                                         int au0, int au1,   // ushort units
                                         int quad, int rsw, int l15,
                                         floatx4 acc[2][NT]) {
  const unsigned short* p0 = hb + au0;
  const unsigned short* p1 = hb + au1;
  half8 ap0[8], ap1[8];
  ALOAD(ap0[0], p0, 0);   ALOAD(ap1[0], p1, 0);
  ALOAD(ap0[1], p0, 64);  ALOAD(ap1[1], p1, 64);
  ALOAD(ap0[2], p0, 128); ALOAD(ap1[2], p1, 128);
  ALOAD(ap0[3], p0, 192); ALOAD(ap1[3], p1, 192);
  ALOAD(ap0[4], p0, 256); ALOAD(ap1[4], p1, 256);
  ALOAD(ap0[5], p0, 320); ALOAD(ap1[5], p1, 320);
  ALOAD(ap0[6], p0, 384); ALOAD(ap1[6], p1, 384);
  ALOAD(ap0[7], p0, 448); ALOAD(ap1[7], p1, 448);
  KSTEP(0, 14)  KSTEP(1, 14)  KSTEP(2, 14)  KSTEP(3, 14)
  KSTEP(4, 14)  KSTEP(5, 14)  KSTEP(6, 14)  KSTEP(7, 14)
  KSTEP(8, 14)  KSTEP(9, 14)  KSTEP(10, 14) KSTEP(11, 14)
  KSTEP(12, 14) KSTEP(13, 14) KSTEP(14, 14) KSTEP(15, 14)
  KSTEP(16, 14) KSTEP(17, 14) KSTEP(18, 14) KSTEP(19, 14)
  KSTEP(20, 14) KSTEP(21, 14) KSTEP(22, 14) KSTEP(23, 14)
  KSTEP(24, 14) KSTEP(25, 12) KSTEP(26, 10) KSTEP(27, 8)
  KSTEP(28, 6)  KSTEP(29, 4)  KSTEP(30, 2)  KSTEP(31, 0)
}

__global__ __launch_bounds__(128, 1) void lstm_persist(
    const float* __restrict__ g0,
    const unsigned short* __restrict__ wbuf,
    const float* __restrict__ b_ih, const float* __restrict__ b_hh,
    const float* __restrict__ b_fc,
    float* __restrict__ out,
    unsigned short* __restrict__ hbuf,   // [2][B][H] fp16 double buffer
    unsigned* __restrict__ ctl) {        // monotonic barrier counter at ctl+64
  extern __shared__ __align__(16) unsigned short sW[];
  const int tid  = threadIdx.x;
  const int wv   = tid >> 6;           // 0..1
  const int lane = tid & 63;
  const int quad = lane >> 4;
  const int l15  = lane & 15;
  const int bid  = blockIdx.x;
  const bool isg = bid < NGB;
  const int rsw  = l15 & 7;
  // role decode: gate block -> (slice, mhalf); fc block -> (fb, mhalf)
  const int sl    = isg ? (bid >> 1) : 0;
  const int fb    = isg ? 0 : ((bid - NGB) >> 1);
  const int mhalf = isg ? (bid & 1) : ((bid - NGB) & 1);
  const int mbase = mhalf * 64;        // this block's 64 batch rows

  unsigned* bar = ctl + 64;            // single flat monotonic counter

  { // stage this block's weight slice into LDS (already fp16 + swizzled in wbuf)
    const uint4* s4 = (const uint4*)(wbuf +
        (size_t)(isg ? sl * 64 : NSL * 64 + fb * 16) * HH);
    uint4* d4 = (uint4*)sW;
    const int n16 = (isg ? 64 * HH : 16 * HH) / 8;
    for (int i = tid; i < n16; i += 128) d4[i] = s4[i];
  }
  __syncthreads();
  const half8* w8 = (const half8*)sW;
  const floatx4 z4 = {0.f, 0.f, 0.f, 0.f};

  if (isg) {
    const int u = sl * 16 + l15;    // hidden unit this lane owns (all 4 gates)
    const float bi = b_ih[u]          + b_hh[u];
    const float bf = b_ih[HH + u]     + b_hh[HH + u];
    const float bg = b_ih[2*HH + u]   + b_hh[2*HH + u];
    const float bo = b_ih[3*HH + u]   + b_hh[3*HH + u];
    float c[2][4] = {{0,0,0,0},{0,0,0,0}};

    // ---- t = 0: gates precomputed in g0; c_prev = 0
#pragma unroll
    for (int mt = 0; mt < 2; ++mt)
#pragma unroll
      for (int r = 0; r < 4; ++r) {
        const int m = mbase + wv * 32 + mt * 16 + quad * 4 + r;
        const float* gr = g0 + (size_t)m * G4;
        float iv = gr[u], gv = gr[2 * HH + u], ov = gr[3 * HH + u];
        float ct = sigf(iv) * tanhf_fast(gv);
        c[mt][r] = ct;
        store_h(hbuf + (size_t)m * HH + u, sigf(ov) * tanhf_fast(ct));
      }
    stepbar(bar, NB);   // publish h(0)

    const int au0 = (mbase + wv * 32 +      l15) * HH + quad * 8;  // ushort units
    const int au1 = (mbase + wv * 32 + 16 + l15) * HH + quad * 8;

    for (int t = 1; t < TT; ++t) {
      const unsigned short* hb = hbuf + (size_t)((t - 1) & 1) * BB * HH;
      unsigned short* hw = hbuf + (size_t)(t & 1) * BB * HH;
      floatx4 acc[2][4] = {{z4, z4, z4, z4}, {z4, z4, z4, z4}};
      gemm2xNT<4>(hb, w8, au0, au1, quad, rsw, l15, acc);
#pragma unroll
      for (int mt = 0; mt < 2; ++mt)
#pragma unroll
        for (int r = 0; r < 4; ++r) {
          float iv = sigf(acc[mt][0][r] + bi);
          float gv = tanhf_fast(acc[mt][1][r] + bg);
          float fv = sigf(acc[mt][2][r] + bf);
          float ov = sigf(acc[mt][3][r] + bo);
          float ct = fv * c[mt][r] + iv * gv;
          c[mt][r] = ct;
          const int m = mbase + wv * 32 + mt * 16 + quad * 4 + r;
          store_h(hw + (size_t)m * HH + u, ov * tanhf_fast(ct));
        }
      stepbar(bar, NB * (unsigned)(t + 1));
    }
  } else {
    // fc block: y_{t-1} = h_{t-1} @ W_fc^T + b_fc, overlapped with step-t gate GEMMs
    const int pcol = fb * 16 + l15;
    const float biasf = b_fc[pcol];
    const int au0 = (mbase + wv * 32 +      l15) * HH + quad * 8;  // ushort units
    const int au1 = (mbase + wv * 32 + 16 + l15) * HH + quad * 8;

    stepbar(bar, NB);   // t = 0: nothing to project yet; wait for h(0)

    for (int t = 1; t <= TT; ++t) {
      const unsigned short* hb = hbuf + (size_t)((t - 1) & 1) * BB * HH;
      floatx4 acc[2][1] = {{z4}, {z4}};
      gemm2xNT<1>(hb, w8, au0, au1, quad, rsw, l15, acc);
#pragma unroll
      for (int mt = 0; mt < 2; ++mt)
#pragma unroll
        for (int r = 0; r < 4; ++r) {
          const int m = mbase + wv * 32 + mt * 16 + quad * 4 + r;
          out[(size_t)m * (TT * PP) + (size_t)(t - 1) * PP + pcol] = acc[mt][0][r] + biasf;
        }
      if (t < TT) stepbar(bar, NB * (unsigned)(t + 1));
    }
  }
}

extern "C" void kernel_launch(void* const* d_in, const int* in_sizes, int n_in,
                              void* d_out, int out_size, void* d_ws, size_t ws_size,
                              hipStream_t stream) {
  const float* z    = (const float*)d_in[1];
  const float* w_ih = (const float*)d_in[2];
  const float* w_hh = (const float*)d_in[3];
  const float* b_ih = (const float*)d_in[4];
  const float* b_hh = (const float*)d_in[5];
  const float* W_fc = (const float*)d_in[6];
  const float* b_fc = (const float*)d_in[7];
  float* out = (float*)d_out;

  // workspace layout (~10.8 MiB total)
  char* ws = (char*)d_ws;
  unsigned*       ctl  = (unsigned*)ws;                                        // 4 KiB ctrl
  unsigned short* hbuf = (unsigned short*)(ws + 4096);                         // 512 KiB
  float*          g0   = (float*)(ws + 4096 + (size_t)2 * BB * HH * 2);        // 2 MiB
  unsigned short* wbuf = (unsigned short*)(ws + 4096 + (size_t)2 * BB * HH * 2
                                              + (size_t)BB * G4 * 4);          // 8.25 MiB

  // allow 128 KiB dynamic LDS (gfx950 has 160 KiB/CU)
  (void)hipFuncSetAttribute(reinterpret_cast<const void*>(lstm_persist),
                            hipFuncAttributeMaxDynamicSharedMemorySize, 160 * 1024);

  hipMemsetAsync(ctl, 0, 4096, stream);
  prep_gates0 <<<dim3(G4), dim3(BB), 0, stream>>>(z, w_ih, b_ih, b_hh, g0);
  prep_weights<<<dim3(NSL * 64 + 8 * 16), dim3(256), 0, stream>>>(w_hh, W_fc, wbuf);
  lstm_persist<<<dim3(NB), dim3(128), 128 * 1024, stream>>>(g0, wbuf, b_ih, b_hh, b_fc,
                                                            out, hbuf, ctl);
}

// Round 7
// 2502.582 us; speedup vs baseline: 1.5086x; 1.0281x over previous
//
#include <hip/hip_runtime.h>
#include <stdint.h>

// Problem constants
#define BB   128      // batch
#define LL   128      // latent dim
#define HH   1024     // hidden
#define G4   4096     // 4*H
#define TT   256      // time steps
#define PP   128      // output cols per step

// 256 blocks x 64 threads (1 wave): slice sl = bid>>2 (16 hidden units),
// batch quarter q = bid&3 (32 rows). 128 KiB weight LDS per block forces
// exactly 1 block/CU -> all 256 CUs used, no co-residency deadlock (256<=256).
// Slices 56..63 are CARRIERS: they also compute the fc projection for their
// quarter (cols (sl-56)*16..+15), reusing the SAME A fragments (h rows) as
// their gate GEMM -- fc B is 32 half8 = constant, preloaded to registers.
#define NSL  64
#define NB   256
#define CARSL 56                 // slices >= CARSL carry fc work

typedef _Float16 half8  __attribute__((ext_vector_type(8)));
typedef float   floatx4 __attribute__((ext_vector_type(4)));

__device__ __forceinline__ float sigf(float x) {
  x = fminf(fmaxf(x, -30.f), 30.f);
  return 1.f / (1.f + __expf(-x));
}
__device__ __forceinline__ float tanhf_fast(float x) {
  x = fminf(fmaxf(x, -15.f), 15.f);
  float e = __expf(2.f * x);
  return (e - 1.f) / (e + 1.f);
}
__device__ __forceinline__ unsigned short f2h(float x) {
  _Float16 h = (_Float16)x;
  return __builtin_bit_cast(unsigned short, h);
}
// agent-scope write-through h store: at LLC once vmcnt(0) drains
__device__ __forceinline__ void store_h(unsigned short* p, float x) {
  __hip_atomic_store(p, f2h(x), __ATOMIC_RELAXED, __HIP_MEMORY_SCOPE_AGENT);
}

// LLC-coherent 16B load: sc0 sc1 -> read at the coherence point.
#define ALOAD(dst, base, IMM)                                              \
  asm volatile("global_load_dwordx4 %0, %1, off offset:%2 sc0 sc1"         \
               : "=&v"(dst) : "v"(base), "n"(IMM) : "memory")

// One pipeline stage: wait for pair kc (counted vmcnt), 2*NT MFMAs, reissue.
// 16-pair ring = 32 loads in flight per wave; with 1 wave/CU this stays
// within per-CU outstanding-request capacity (r4's regression was 4 waves
// x 32 = 128 outstanding/CU). B tiles nt<NGATE come from LDS (swizzled);
// nt>=NGATE come from the fcb register array (constant fc weights).
// The "+v" ties make the MFMAs data-depend on the wait (rule #18).
#define KSTEP(kc, WN)                                                      \
  {                                                                        \
    asm volatile("s_waitcnt vmcnt(%2)"                                     \
                 : "+v"(ap0[(kc) & 15]), "+v"(ap1[(kc) & 15]) : "n"(WN));  \
    half8 a0 = ap0[(kc) & 15], a1 = ap1[(kc) & 15];                        \
    const int sw = ((kc) * 4 + quad) ^ rsw;                                \
    _Pragma("unroll")                                                      \
    for (int nt = 0; nt < NT; ++nt) {                                      \
      half8 b = (nt < NGATE) ? w8[(nt * 16 + l15) * 128 + sw] : fcb[kc];   \
      acc[0][nt] = __builtin_amdgcn_mfma_f32_16x16x32_f16(a0, b, acc[0][nt], 0, 0, 0); \
      acc[1][nt] = __builtin_amdgcn_mfma_f32_16x16x32_f16(a1, b, acc[1][nt], 0, 0, 0); \
    }                                                                      \
    if ((kc) < 16) {                                                       \
      ALOAD(ap0[(kc) & 15], p0, ((kc) + 16) * 64);                         \
      ALOAD(ap1[(kc) & 15], p1, ((kc) + 16) * 64);                         \
    }                                                                      \
  }

// Distributed flat barrier: 4 monotonic counters on 4 LLC lines 16 KiB apart
// (parallel arrival streams, ~64 adds/line/step instead of 256 on one line).
// Zero cache-maintenance ops (h stores are write-through agent-scope; reads
// are sc0sc1 at the coherence point).
__device__ __forceinline__ void stepbar4(unsigned* ctl, int myline, unsigned s) {
  __syncthreads();
  if (threadIdx.x == 0) {
    asm volatile("s_waitcnt vmcnt(0)" ::: "memory");   // h stores at LLC
    __hip_atomic_fetch_add(ctl + myline * 4096, 1u, __ATOMIC_RELAXED,
                           __HIP_MEMORY_SCOPE_AGENT);
    const unsigned tgt = 64u * s;
    for (;;) {
      unsigned a0 = __hip_atomic_load(ctl,          __ATOMIC_RELAXED, __HIP_MEMORY_SCOPE_AGENT);
      unsigned a1 = __hip_atomic_load(ctl + 4096,   __ATOMIC_RELAXED, __HIP_MEMORY_SCOPE_AGENT);
      unsigned a2 = __hip_atomic_load(ctl + 8192,   __ATOMIC_RELAXED, __HIP_MEMORY_SCOPE_AGENT);
      unsigned a3 = __hip_atomic_load(ctl + 12288,  __ATOMIC_RELAXED, __HIP_MEMORY_SCOPE_AGENT);
      unsigned m01 = a0 < a1 ? a0 : a1;
      unsigned m23 = a2 < a3 ? a2 : a3;
      if ((m01 < m23 ? m01 : m23) >= tgt) break;
      __builtin_amdgcn_s_sleep(1);
    }
  }
  __syncthreads();
}

// gates0 = z @ w_ih^T + b_ih + b_hh   (step-0 gates; h0=c0=0, x=0 for t>=1)
__global__ void prep_gates0(const float* __restrict__ z, const float* __restrict__ w_ih,
                            const float* __restrict__ b_ih, const float* __restrict__ b_hh,
                            float* __restrict__ g0) {
  int j = blockIdx.x;     // 0..4095
  int b = threadIdx.x;    // 0..127
  const float* zr = z + b * LL;
  const float* wr = w_ih + (size_t)j * LL;
  float s = 0.f;
#pragma unroll 4
  for (int k = 0; k < LL; ++k) s += zr[k] * wr[k];
  g0[(size_t)b * G4 + j] = s + b_ih[j] + b_hh[j];
}

// Convert w_hh to fp16 in the persistent kernel's LDS layout.
// Weight slice sl owns units u = sl*16 .. sl*16+15; LDS rows (tile*16+nl) for
// tile 0..3 = gates i,g,f,o of unit nl. Each row's 8-elem k-chunks are
// XOR-swizzled by (nl&7) so the wave's B-reads are same-bank-free.
__global__ void prep_weights(const float* __restrict__ w_hh,
                             unsigned short* __restrict__ wbuf) {
  int R = blockIdx.x;                 // 0..4095 gate rows
  int sl = R >> 6, rr = R & 63, tile = rr >> 4, nl = rr & 15;
  int g = (tile == 0) ? 0 : (tile == 1) ? 2 : (tile == 2) ? 1 : 3;  // i,g,f,o
  const float* src = w_hh + (size_t)(g * HH + sl * 16 + nl) * HH;
  int rsw = nl & 7;
  unsigned short* dst = wbuf + (size_t)R * HH;
  for (int k = threadIdx.x; k < HH; k += blockDim.x) {
    int dk = (((k >> 3) ^ rsw) << 3) | (k & 7);
    _Float16 v = (_Float16)src[k];
    dst[dk] = __builtin_bit_cast(unsigned short, v);
  }
}

// One K=1024 MFMA pass: C[2 mtiles x NT ntiles]. A streamed from global h via
// sc0sc1 16B loads, hand-pipelined 16-deep per m-stream with counted vmcnt.
// B from LDS (gate tiles) and/or fcb registers (fc tile).
template <int NT, int NGATE>
__device__ __forceinline__ void gemmK(const unsigned short* __restrict__ hb,
                                      const half8* __restrict__ w8,
                                      const half8 (&fcb)[32],
                                      int au0, int au1,   // ushort units
                                      int quad, int rsw, int l15,
                                      floatx4 acc[2][NT]) {
  const unsigned short* p0 = hb + au0;
  const unsigned short* p1 = hb + au1;
  half8 ap0[16], ap1[16];
  ALOAD(ap0[0],  p0, 0);    ALOAD(ap1[0],  p1, 0);
  ALOAD(ap0[1],  p0, 64);   ALOAD(ap1[1],  p1, 64);
  ALOAD(ap0[2],  p0, 128);  ALOAD(ap1[2],  p1, 128);
  ALOAD(ap0[3],  p0, 192);  ALOAD(ap1[3],  p1, 192);
  ALOAD(ap0[4],  p0, 256);  ALOAD(ap1[4],  p1, 256);
  ALOAD(ap0[5],  p0, 320);  ALOAD(ap1[5],  p1, 320);
  ALOAD(ap0[6],  p0, 384);  ALOAD(ap1[6],  p1, 384);
  ALOAD(ap0[7],  p0, 448);  ALOAD(ap1[7],  p1, 448);
  ALOAD(ap0[8],  p0, 512);  ALOAD(ap1[8],  p1, 512);
  ALOAD(ap0[9],  p0, 576);  ALOAD(ap1[9],  p1, 576);
  ALOAD(ap0[10], p0, 640);  ALOAD(ap1[10], p1, 640);
  ALOAD(ap0[11], p0, 704);  ALOAD(ap1[11], p1, 704);
  ALOAD(ap0[12], p0, 768);  ALOAD(ap1[12], p1, 768);
  ALOAD(ap0[13], p0, 832);  ALOAD(ap1[13], p1, 832);
  ALOAD(ap0[14], p0, 896);  ALOAD(ap1[14], p1, 896);
  ALOAD(ap0[15], p0, 960);  ALOAD(ap1[15], p1, 960);
  KSTEP(0, 30)  KSTEP(1, 30)  KSTEP(2, 30)  KSTEP(3, 30)
  KSTEP(4, 30)  KSTEP(5, 30)  KSTEP(6, 30)  KSTEP(7, 30)
  KSTEP(8, 30)  KSTEP(9, 30)  KSTEP(10, 30) KSTEP(11, 30)
  KSTEP(12, 30) KSTEP(13, 30) KSTEP(14, 30) KSTEP(15, 30)
  KSTEP(16, 30) KSTEP(17, 28) KSTEP(18, 26) KSTEP(19, 24)
  KSTEP(20, 22) KSTEP(21, 20) KSTEP(22, 18) KSTEP(23, 16)
  KSTEP(24, 14) KSTEP(25, 12) KSTEP(26, 10) KSTEP(27, 8)
  KSTEP(28, 6)  KSTEP(29, 4)  KSTEP(30, 2)  KSTEP(31, 0)
}

__global__ __launch_bounds__(64, 1) void lstm_persist(
    const float* __restrict__ g0,
    const unsigned short* __restrict__ wbuf,
    const float* __restrict__ b_ih, const float* __restrict__ b_hh,
    const float* __restrict__ W_fc, const float* __restrict__ b_fc,
    float* __restrict__ out,
    unsigned short* __restrict__ hbuf,   // [2][B][H] fp16 double buffer
    unsigned* __restrict__ ctl) {        // 4 barrier lines, 16 KiB apart
  extern __shared__ __align__(16) unsigned short sW[];
  const int tid  = threadIdx.x;          // 0..63 (one wave)
  const int lane = tid;
  const int quad = lane >> 4;
  const int l15  = lane & 15;
  const int bid  = blockIdx.x;
  const int sl   = bid >> 2;             // weight slice 0..63
  const int q    = bid & 3;              // batch quarter
  const int mbase = q * 32;
  const int rsw  = l15 & 7;
  const bool carrier = (sl >= CARSL);
  const int pcol = (sl - CARSL) * 16 + l15;   // fc col (carriers only)

  { // stage this block's weight slice into LDS (fp16 + swizzled in wbuf)
    const uint4* s4 = (const uint4*)(wbuf + (size_t)sl * 64 * HH);
    uint4* d4 = (uint4*)sW;
    for (int i = tid; i < 64 * HH / 8; i += 64) d4[i] = s4[i];
  }
  __syncthreads();
  const half8* w8 = (const half8*)sW;
  const floatx4 z4 = {0.f, 0.f, 0.f, 0.f};

  // carriers: preload fc B fragments (constant across steps) into registers.
  // lane's fragment row = pcol, k-elems = kc*32 + quad*8 .. +7.
  half8 fcb[32];
  float biasf = 0.f;
  if (carrier) {
    biasf = b_fc[pcol];
    const float* wp = W_fc + (size_t)pcol * HH + quad * 8;
#pragma unroll
    for (int kc = 0; kc < 32; ++kc) {
      float4 f0 = *(const float4*)(wp + kc * 32);
      float4 f1 = *(const float4*)(wp + kc * 32 + 4);
      half8 hv;
      hv[0] = (_Float16)f0.x; hv[1] = (_Float16)f0.y;
      hv[2] = (_Float16)f0.z; hv[3] = (_Float16)f0.w;
      hv[4] = (_Float16)f1.x; hv[5] = (_Float16)f1.y;
      hv[6] = (_Float16)f1.z; hv[7] = (_Float16)f1.w;
      fcb[kc] = hv;
    }
  }

  const int u = sl * 16 + l15;    // hidden unit this lane owns (all 4 gates)
  const float bi = b_ih[u]          + b_hh[u];
  const float bf = b_ih[HH + u]     + b_hh[HH + u];
  const float bg = b_ih[2*HH + u]   + b_hh[2*HH + u];
  const float bo = b_ih[3*HH + u]   + b_hh[3*HH + u];
  float c[2][4] = {{0,0,0,0},{0,0,0,0}};

  // ---- t = 0: gates precomputed in g0; c_prev = 0
#pragma unroll
  for (int mt = 0; mt < 2; ++mt)
#pragma unroll
    for (int r = 0; r < 4; ++r) {
      const int m = mbase + mt * 16 + quad * 4 + r;
      const float* gr = g0 + (size_t)m * G4;
      float iv = gr[u], gv = gr[2 * HH + u], ov = gr[3 * HH + u];
      float ct = sigf(iv) * tanhf_fast(gv);
      c[mt][r] = ct;
      store_h(hbuf + (size_t)m * HH + u, sigf(ov) * tanhf_fast(ct));
    }
  stepbar4(ctl, bid & 3, 1u);   // publish h(0)

  const int au0 = (mbase +      l15) * HH + quad * 8;  // ushort units
  const int au1 = (mbase + 16 + l15) * HH + quad * 8;

  if (carrier) {
    for (int t = 1; t < TT; ++t) {
      const unsigned short* hb = hbuf + (size_t)((t - 1) & 1) * BB * HH;
      unsigned short* hw = hbuf + (size_t)(t & 1) * BB * HH;
      floatx4 acc[2][5] = {{z4, z4, z4, z4, z4}, {z4, z4, z4, z4, z4}};
      gemmK<5, 4>(hb, w8, fcb, au0, au1, quad, rsw, l15, acc);
#pragma unroll
      for (int mt = 0; mt < 2; ++mt)
#pragma unroll
        for (int r = 0; r < 4; ++r) {
          float iv = sigf(acc[mt][0][r] + bi);
          float gv = tanhf_fast(acc[mt][1][r] + bg);
          float fv = sigf(acc[mt][2][r] + bf);
          float ov = sigf(acc[mt][3][r] + bo);
          float ct = fv * c[mt][r] + iv * gv;
          c[mt][r] = ct;
          const int m = mbase + mt * 16 + quad * 4 + r;
          store_h(hw + (size_t)m * HH + u, ov * tanhf_fast(ct));
          // fc output for step t-1 (same A = h(t-1))
          out[(size_t)m * (TT * PP) + (size_t)(t - 1) * PP + pcol] =
              acc[mt][4][r] + biasf;
        }
      stepbar4(ctl, bid & 3, (unsigned)(t + 1));
    }
    // final fc column: y_{TT-1} = h(TT-1) @ W_fc^T + b_fc  (h(TT-1) visible
    // after the last barrier; no one depends on this, no further barrier)
    {
      const unsigned short* hb = hbuf + (size_t)((TT - 1) & 1) * BB * HH;
      floatx4 acc[2][1] = {{z4}, {z4}};
      gemmK<1, 0>(hb, w8, fcb, au0, au1, quad, rsw, l15, acc);
#pragma unroll
      for (int mt = 0; mt < 2; ++mt)
#pragma unroll
        for (int r = 0; r < 4; ++r) {
          const int m = mbase + mt * 16 + quad * 4 + r;
          out[(size_t)m * (TT * PP) + (size_t)(TT - 1) * PP + pcol] =
              acc[mt][0][r] + biasf;
        }
    }
  } else {
    for (int t = 1; t < TT; ++t) {
      const unsigned short* hb = hbuf + (size_t)((t - 1) & 1) * BB * HH;
      unsigned short* hw = hbuf + (size_t)(t & 1) * BB * HH;
      floatx4 acc[2][4] = {{z4, z4, z4, z4}, {z4, z4, z4, z4}};
      gemmK<4, 4>(hb, w8, fcb, au0, au1, quad, rsw, l15, acc);
#pragma unroll
      for (int mt = 0; mt < 2; ++mt)
#pragma unroll
        for (int r = 0; r < 4; ++r) {
          float iv = sigf(acc[mt][0][r] + bi);
          float gv = tanhf_fast(acc[mt][1][r] + bg);
          float fv = sigf(acc[mt][2][r] + bf);
          float ov = sigf(acc[mt][3][r] + bo);
          float ct = fv * c[mt][r] + iv * gv;
          c[mt][r] = ct;
          const int m = mbase + mt * 16 + quad * 4 + r;
          store_h(hw + (size_t)m * HH + u, ov * tanhf_fast(ct));
        }
      stepbar4(ctl, bid & 3, (unsigned)(t + 1));
    }
  }
}

extern "C" void kernel_launch(void* const* d_in, const int* in_sizes, int n_in,
                              void* d_out, int out_size, void* d_ws, size_t ws_size,
                              hipStream_t stream) {
  const float* z    = (const float*)d_in[1];
  const float* w_ih = (const float*)d_in[2];
  const float* w_hh = (const float*)d_in[3];
  const float* b_ih = (const float*)d_in[4];
  const float* b_hh = (const float*)d_in[5];
  const float* W_fc = (const float*)d_in[6];
  const float* b_fc = (const float*)d_in[7];
  float* out = (float*)d_out;

  // workspace layout (~10.8 MiB total)
  char* ws = (char*)d_ws;
  unsigned*       ctl  = (unsigned*)ws;                                        // 64 KiB (4 barrier lines)
  unsigned short* hbuf = (unsigned short*)(ws + 65536);                        // 512 KiB
  float*          g0   = (float*)(ws + 65536 + (size_t)2 * BB * HH * 2);       // 2 MiB
  unsigned short* wbuf = (unsigned short*)(ws + 65536 + (size_t)2 * BB * HH * 2
                                              + (size_t)BB * G4 * 4);          // 8 MiB

  // allow 128 KiB dynamic LDS (gfx950 has 160 KiB/CU)
  (void)hipFuncSetAttribute(reinterpret_cast<const void*>(lstm_persist),
                            hipFuncAttributeMaxDynamicSharedMemorySize, 160 * 1024);

  hipMemsetAsync(ctl, 0, 65536, stream);
  prep_gates0 <<<dim3(G4), dim3(BB), 0, stream>>>(z, w_ih, b_ih, b_hh, g0);
  prep_weights<<<dim3(NSL * 64), dim3(256), 0, stream>>>(w_hh, wbuf);
  lstm_persist<<<dim3(NB), dim3(64), 128 * 1024, stream>>>(g0, wbuf, b_ih, b_hh,
                                                           W_fc, b_fc, out, hbuf, ctl);
}

// Round 8
// 2348.973 us; speedup vs baseline: 1.6072x; 1.0654x over previous
//
#include <hip/hip_runtime.h>
#include <stdint.h>

// Problem constants
#define BB   128      // batch
#define LL   128      // latent dim
#define HH   1024     // hidden
#define G4   4096     // 4*H
#define TT   256      // time steps
#define PP   128      // output cols per step

// 256 blocks x 64 threads (1 wave): slice sl = bid>>2 (16 hidden units),
// batch quarter q = bid&3 (32 rows). 128 KiB weight LDS per block forces
// exactly 1 block/CU -> all 256 CUs used (256<=256, co-residency as in r7).
// Slices 56..63 are CARRIERS: they also compute the fc projection for their
// quarter (cols (sl-56)*16..+15), reusing the SAME A fragments as the gate
// GEMM; fc B is 32 half8 = constant, preloaded to registers.
//
// SYNC (new in r8): the 4 batch-quarters are INDEPENDENT recurrences
// (row m of h is written and read only by quarter m/32). Per-quarter
// single-writer flag barrier: flag[sl] = step marker, stored (not RMW'd)
// by its one producer after vmcnt(0); consumers poll all 64 flags with one
// wave-wide load (lane i reads flag[i], __all(>=t)). Replaces 256 serialized
// atomicAdds + global straggler coupling of the old counter barrier.
#define NSL  64
#define NB   256
#define CARSL 56                 // slices >= CARSL carry fc work

typedef _Float16 half8  __attribute__((ext_vector_type(8)));
typedef float   floatx4 __attribute__((ext_vector_type(4)));

__device__ __forceinline__ float sigf(float x) {
  x = fminf(fmaxf(x, -30.f), 30.f);
  return 1.f / (1.f + __expf(-x));
}
__device__ __forceinline__ float tanhf_fast(float x) {
  x = fminf(fmaxf(x, -15.f), 15.f);
  float e = __expf(2.f * x);
  return (e - 1.f) / (e + 1.f);
}
__device__ __forceinline__ unsigned short f2h(float x) {
  _Float16 h = (_Float16)x;
  return __builtin_bit_cast(unsigned short, h);
}
// agent-scope write-through h store: at LLC once vmcnt(0) drains
__device__ __forceinline__ void store_h(unsigned short* p, float x) {
  __hip_atomic_store(p, f2h(x), __ATOMIC_RELAXED, __HIP_MEMORY_SCOPE_AGENT);
}

// LLC-coherent 16B load: sc0 sc1 -> read at the coherence point.
#define ALOAD(dst, base, IMM)                                              \
  asm volatile("global_load_dwordx4 %0, %1, off offset:%2 sc0 sc1"         \
               : "=&v"(dst) : "v"(base), "n"(IMM) : "memory")

// One pipeline stage: wait for pair kc (counted vmcnt), 2*NT MFMAs, reissue.
// 16-pair ring = 32 loads in flight (1 wave/CU -> within per-CU capacity).
// B tiles nt<NGATE from LDS (swizzled); nt>=NGATE from fcb registers.
// The "+v" ties make the MFMAs data-depend on the wait (rule #18).
#define KSTEP(kc, WN)                                                      \
  {                                                                        \
    asm volatile("s_waitcnt vmcnt(%2)"                                     \
                 : "+v"(ap0[(kc) & 15]), "+v"(ap1[(kc) & 15]) : "n"(WN));  \
    half8 a0 = ap0[(kc) & 15], a1 = ap1[(kc) & 15];                        \
    const int sw = ((kc) * 4 + quad) ^ rsw;                                \
    _Pragma("unroll")                                                      \
    for (int nt = 0; nt < NT; ++nt) {                                      \
      half8 b = (nt < NGATE) ? w8[(nt * 16 + l15) * 128 + sw] : fcb[kc];   \
      acc[0][nt] = __builtin_amdgcn_mfma_f32_16x16x32_f16(a0, b, acc[0][nt], 0, 0, 0); \
      acc[1][nt] = __builtin_amdgcn_mfma_f32_16x16x32_f16(a1, b, acc[1][nt], 0, 0, 0); \
    }                                                                      \
    if ((kc) < 16) {                                                       \
      ALOAD(ap0[(kc) & 15], p0, ((kc) + 16) * 64);                         \
      ALOAD(ap1[(kc) & 15], p1, ((kc) + 16) * 64);                         \
    }                                                                      \
  }

// Producer arrival: drain own stores to LLC, then ONE single-writer flag
// store (no RMW, no shared-line contention).
__device__ __forceinline__ void publish(unsigned* qf, int sl, unsigned v, int lane) {
  asm volatile("s_waitcnt vmcnt(0)" ::: "memory");   // h stores at LLC
  if (lane == 0)
    __hip_atomic_store(qf + sl, v, __ATOMIC_RELAXED, __HIP_MEMORY_SCOPE_AGENT);
}
// Consumer wait: wave-wide poll of the quarter's 64 flags (lane i reads
// flag[i]; 4 coalesced lines per poll round). The compiler-inserted
// vmcnt(0) before using v also drains our own flag store -> the gemm's
// counted vmcnt ring starts from a clean 0 outstanding.
__device__ __forceinline__ void waitq(const unsigned* qf, unsigned tgt, int lane) {
  for (;;) {
    unsigned v = __hip_atomic_load(qf + lane, __ATOMIC_RELAXED, __HIP_MEMORY_SCOPE_AGENT);
    if (__all(v >= tgt)) break;
    __builtin_amdgcn_s_sleep(1);
  }
}

// gates0 = z @ w_ih^T + b_ih + b_hh   (step-0 gates; h0=c0=0, x=0 for t>=1)
__global__ void prep_gates0(const float* __restrict__ z, const float* __restrict__ w_ih,
                            const float* __restrict__ b_ih, const float* __restrict__ b_hh,
                            float* __restrict__ g0) {
  int j = blockIdx.x;     // 0..4095
  int b = threadIdx.x;    // 0..127
  const float* zr = z + b * LL;
  const float* wr = w_ih + (size_t)j * LL;
  float s = 0.f;
#pragma unroll 4
  for (int k = 0; k < LL; ++k) s += zr[k] * wr[k];
  g0[(size_t)b * G4 + j] = s + b_ih[j] + b_hh[j];
}

// Convert w_hh to fp16 in the persistent kernel's LDS layout.
// Weight slice sl owns units u = sl*16 .. sl*16+15; LDS rows (tile*16+nl) for
// tile 0..3 = gates i,g,f,o of unit nl. Each row's 8-elem k-chunks are
// XOR-swizzled by (nl&7) so the wave's B-reads are same-bank-free.
__global__ void prep_weights(const float* __restrict__ w_hh,
                             unsigned short* __restrict__ wbuf) {
  int R = blockIdx.x;                 // 0..4095 gate rows
  int sl = R >> 6, rr = R & 63, tile = rr >> 4, nl = rr & 15;
  int g = (tile == 0) ? 0 : (tile == 1) ? 2 : (tile == 2) ? 1 : 3;  // i,g,f,o
  const float* src = w_hh + (size_t)(g * HH + sl * 16 + nl) * HH;
  int rsw = nl & 7;
  unsigned short* dst = wbuf + (size_t)R * HH;
  for (int k = threadIdx.x; k < HH; k += blockDim.x) {
    int dk = (((k >> 3) ^ rsw) << 3) | (k & 7);
    _Float16 v = (_Float16)src[k];
    dst[dk] = __builtin_bit_cast(unsigned short, v);
  }
}

// One K=1024 MFMA pass: C[2 mtiles x NT ntiles]. A streamed from global h via
// sc0sc1 16B loads, hand-pipelined 16-deep per m-stream with counted vmcnt.
// B from LDS (gate tiles) and/or fcb registers (fc tile).
template <int NT, int NGATE>
__device__ __forceinline__ void gemmK(const unsigned short* __restrict__ hb,
                                      const half8* __restrict__ w8,
                                      const half8 (&fcb)[32],
                                      int au0, int au1,   // ushort units
                                      int quad, int rsw, int l15,
                                      floatx4 acc[2][NT]) {
  const unsigned short* p0 = hb + au0;
  const unsigned short* p1 = hb + au1;
  half8 ap0[16], ap1[16];
  ALOAD(ap0[0],  p0, 0);    ALOAD(ap1[0],  p1, 0);
  ALOAD(ap0[1],  p0, 64);   ALOAD(ap1[1],  p1, 64);
  ALOAD(ap0[2],  p0, 128);  ALOAD(ap1[2],  p1, 128);
  ALOAD(ap0[3],  p0, 192);  ALOAD(ap1[3],  p1, 192);
  ALOAD(ap0[4],  p0, 256);  ALOAD(ap1[4],  p1, 256);
  ALOAD(ap0[5],  p0, 320);  ALOAD(ap1[5],  p1, 320);
  ALOAD(ap0[6],  p0, 384);  ALOAD(ap1[6],  p1, 384);
  ALOAD(ap0[7],  p0, 448);  ALOAD(ap1[7],  p1, 448);
  ALOAD(ap0[8],  p0, 512);  ALOAD(ap1[8],  p1, 512);
  ALOAD(ap0[9],  p0, 576);  ALOAD(ap1[9],  p1, 576);
  ALOAD(ap0[10], p0, 640);  ALOAD(ap1[10], p1, 640);
  ALOAD(ap0[11], p0, 704);  ALOAD(ap1[11], p1, 704);
  ALOAD(ap0[12], p0, 768);  ALOAD(ap1[12], p1, 768);
  ALOAD(ap0[13], p0, 832);  ALOAD(ap1[13], p1, 832);
  ALOAD(ap0[14], p0, 896);  ALOAD(ap1[14], p1, 896);
  ALOAD(ap0[15], p0, 960);  ALOAD(ap1[15], p1, 960);
  KSTEP(0, 30)  KSTEP(1, 30)  KSTEP(2, 30)  KSTEP(3, 30)
  KSTEP(4, 30)  KSTEP(5, 30)  KSTEP(6, 30)  KSTEP(7, 30)
  KSTEP(8, 30)  KSTEP(9, 30)  KSTEP(10, 30) KSTEP(11, 30)
  KSTEP(12, 30) KSTEP(13, 30) KSTEP(14, 30) KSTEP(15, 30)
  KSTEP(16, 30) KSTEP(17, 28) KSTEP(18, 26) KSTEP(19, 24)
  KSTEP(20, 22) KSTEP(21, 20) KSTEP(22, 18) KSTEP(23, 16)
  KSTEP(24, 14) KSTEP(25, 12) KSTEP(26, 10) KSTEP(27, 8)
  KSTEP(28, 6)  KSTEP(29, 4)  KSTEP(30, 2)  KSTEP(31, 0)
}

__global__ __launch_bounds__(64, 1) void lstm_persist(
    const float* __restrict__ g0,
    const unsigned short* __restrict__ wbuf,
    const float* __restrict__ b_ih, const float* __restrict__ b_hh,
    const float* __restrict__ W_fc, const float* __restrict__ b_fc,
    float* __restrict__ out,
    unsigned short* __restrict__ hbuf,   // [2][B][H] fp16 double buffer
    unsigned* __restrict__ ctl) {        // 4 quarters x 1024 words (flags)
  extern __shared__ __align__(16) unsigned short sW[];
  const int tid  = threadIdx.x;          // 0..63 (one wave)
  const int lane = tid;
  const int quad = lane >> 4;
  const int l15  = lane & 15;
  const int bid  = blockIdx.x;
  const int sl   = bid >> 2;             // weight slice 0..63
  const int q    = bid & 3;              // batch quarter
  const int mbase = q * 32;
  const int rsw  = l15 & 7;
  const bool carrier = (sl >= CARSL);
  const int pcol = (sl - CARSL) * 16 + l15;   // fc col (carriers only)

  unsigned* qf = ctl + q * 1024;         // this quarter's 64 flags

  { // stage this block's weight slice into LDS (fp16 + swizzled in wbuf)
    const uint4* s4 = (const uint4*)(wbuf + (size_t)sl * 64 * HH);
    uint4* d4 = (uint4*)sW;
    for (int i = tid; i < 64 * HH / 8; i += 64) d4[i] = s4[i];
  }
  __syncthreads();
  const half8* w8 = (const half8*)sW;
  const floatx4 z4 = {0.f, 0.f, 0.f, 0.f};

  // carriers: preload fc B fragments (constant across steps) into registers.
  half8 fcb[32];
  float biasf = 0.f;
  if (carrier) {
    biasf = b_fc[pcol];
    const float* wp = W_fc + (size_t)pcol * HH + quad * 8;
#pragma unroll
    for (int kc = 0; kc < 32; ++kc) {
      float4 f0 = *(const float4*)(wp + kc * 32);
      float4 f1 = *(const float4*)(wp + kc * 32 + 4);
      half8 hv;
      hv[0] = (_Float16)f0.x; hv[1] = (_Float16)f0.y;
      hv[2] = (_Float16)f0.z; hv[3] = (_Float16)f0.w;
      hv[4] = (_Float16)f1.x; hv[5] = (_Float16)f1.y;
      hv[6] = (_Float16)f1.z; hv[7] = (_Float16)f1.w;
      fcb[kc] = hv;
    }
  }

  const int u = sl * 16 + l15;    // hidden unit this lane owns (all 4 gates)
  const float bi = b_ih[u]          + b_hh[u];
  const float bf = b_ih[HH + u]     + b_hh[HH + u];
  const float bg = b_ih[2*HH + u]   + b_hh[2*HH + u];
  const float bo = b_ih[3*HH + u]   + b_hh[3*HH + u];
  float c[2][4] = {{0,0,0,0},{0,0,0,0}};

  // ---- t = 0: gates precomputed in g0; c_prev = 0
#pragma unroll
  for (int mt = 0; mt < 2; ++mt)
#pragma unroll
    for (int r = 0; r < 4; ++r) {
      const int m = mbase + mt * 16 + quad * 4 + r;
      const float* gr = g0 + (size_t)m * G4;
      float iv = gr[u], gv = gr[2 * HH + u], ov = gr[3 * HH + u];
      float ct = sigf(iv) * tanhf_fast(gv);
      c[mt][r] = ct;
      store_h(hbuf + (size_t)m * HH + u, sigf(ov) * tanhf_fast(ct));
    }
  publish(qf, sl, 1u, lane);     // h(0) visible -> marker 1

  const int au0 = (mbase +      l15) * HH + quad * 8;  // ushort units
  const int au1 = (mbase + 16 + l15) * HH + quad * 8;

  if (carrier) {
    for (int t = 1; t < TT; ++t) {
      waitq(qf, (unsigned)t, lane);         // all quarter peers published h(t-1)
      const unsigned short* hb = hbuf + (size_t)((t - 1) & 1) * BB * HH;
      unsigned short* hw = hbuf + (size_t)(t & 1) * BB * HH;
      floatx4 acc[2][5] = {{z4, z4, z4, z4, z4}, {z4, z4, z4, z4, z4}};
      gemmK<5, 4>(hb, w8, fcb, au0, au1, quad, rsw, l15, acc);
#pragma unroll
      for (int mt = 0; mt < 2; ++mt)
#pragma unroll
        for (int r = 0; r < 4; ++r) {
          float iv = sigf(acc[mt][0][r] + bi);
          float gv = tanhf_fast(acc[mt][1][r] + bg);
          float fv = sigf(acc[mt][2][r] + bf);
          float ov = sigf(acc[mt][3][r] + bo);
          float ct = fv * c[mt][r] + iv * gv;
          c[mt][r] = ct;
          const int m = mbase + mt * 16 + quad * 4 + r;
          store_h(hw + (size_t)m * HH + u, ov * tanhf_fast(ct));
          // fc output for step t-1 (same A = h(t-1))
          out[(size_t)m * (TT * PP) + (size_t)(t - 1) * PP + pcol] =
              acc[mt][4][r] + biasf;
        }
      publish(qf, sl, (unsigned)(t + 1), lane);
    }
    // final fc column: y_{TT-1} = h(TT-1) @ W_fc^T + b_fc
    waitq(qf, (unsigned)TT, lane);
    {
      const unsigned short* hb = hbuf + (size_t)((TT - 1) & 1) * BB * HH;
      floatx4 acc[2][1] = {{z4}, {z4}};
      gemmK<1, 0>(hb, w8, fcb, au0, au1, quad, rsw, l15, acc);
#pragma unroll
      for (int mt = 0; mt < 2; ++mt)
#pragma unroll
        for (int r = 0; r < 4; ++r) {
          const int m = mbase + mt * 16 + quad * 4 + r;
          out[(size_t)m * (TT * PP) + (size_t)(TT - 1) * PP + pcol] =
              acc[mt][0][r] + biasf;
        }
    }
  } else {
    for (int t = 1; t < TT; ++t) {
      waitq(qf, (unsigned)t, lane);
      const unsigned short* hb = hbuf + (size_t)((t - 1) & 1) * BB * HH;
      unsigned short* hw = hbuf + (size_t)(t & 1) * BB * HH;
      floatx4 acc[2][4] = {{z4, z4, z4, z4}, {z4, z4, z4, z4}};
      gemmK<4, 4>(hb, w8, fcb, au0, au1, quad, rsw, l15, acc);
#pragma unroll
      for (int mt = 0; mt < 2; ++mt)
#pragma unroll
        for (int r = 0; r < 4; ++r) {
          float iv = sigf(acc[mt][0][r] + bi);
          float gv = tanhf_fast(acc[mt][1][r] + bg);
          float fv = sigf(acc[mt][2][r] + bf);
          float ov = sigf(acc[mt][3][r] + bo);
          float ct = fv * c[mt][r] + iv * gv;
          c[mt][r] = ct;
          const int m = mbase + mt * 16 + quad * 4 + r;
          store_h(hw + (size_t)m * HH + u, ov * tanhf_fast(ct));
        }
      publish(qf, sl, (unsigned)(t + 1), lane);
    }
  }
}

extern "C" void kernel_launch(void* const* d_in, const int* in_sizes, int n_in,
                              void* d_out, int out_size, void* d_ws, size_t ws_size,
                              hipStream_t stream) {
  const float* z    = (const float*)d_in[1];
  const float* w_ih = (const float*)d_in[2];
  const float* w_hh = (const float*)d_in[3];
  const float* b_ih = (const float*)d_in[4];
  const float* b_hh = (const float*)d_in[5];
  const float* W_fc = (const float*)d_in[6];
  const float* b_fc = (const float*)d_in[7];
  float* out = (float*)d_out;

  // workspace layout (~10.8 MiB total)
  char* ws = (char*)d_ws;
  unsigned*       ctl  = (unsigned*)ws;                                        // 16 KiB (4x1024 flag words)
  unsigned short* hbuf = (unsigned short*)(ws + 65536);                        // 512 KiB
  float*          g0   = (float*)(ws + 65536 + (size_t)2 * BB * HH * 2);       // 2 MiB
  unsigned short* wbuf = (unsigned short*)(ws + 65536 + (size_t)2 * BB * HH * 2
                                              + (size_t)BB * G4 * 4);          // 8 MiB

  // allow 128 KiB dynamic LDS (gfx950 has 160 KiB/CU)
  (void)hipFuncSetAttribute(reinterpret_cast<const void*>(lstm_persist),
                            hipFuncAttributeMaxDynamicSharedMemorySize, 160 * 1024);

  hipMemsetAsync(ctl, 0, 65536, stream);
  prep_gates0 <<<dim3(G4), dim3(BB), 0, stream>>>(z, w_ih, b_ih, b_hh, g0);
  prep_weights<<<dim3(NSL * 64), dim3(256), 0, stream>>>(w_hh, wbuf);
  lstm_persist<<<dim3(NB), dim3(64), 128 * 1024, stream>>>(g0, wbuf, b_ih, b_hh,
                                                           W_fc, b_fc, out, hbuf, ctl);
}

// Round 10
// 2329.734 us; speedup vs baseline: 1.6205x; 1.0083x over previous
//
#include <hip/hip_runtime.h>
#include <stdint.h>

// Problem constants
#define BB   128      // batch
#define LL   128      // latent dim
#define HH   1024     // hidden
#define G4   4096     // 4*H
#define TT   256      // time steps
#define PP   128      // output cols per step

#define NSL  64
#define NB   256
#define CARSL 56                 // slices >= CARSL carry fc work

// r10: time-extended h buffer kills L2 staleness structurally.
// hbuf[t][B][H] (256 slots, 64 MiB): every step writes FRESH addresses, so no
// L2 line can ever be a stale copy. A-reads switch from sc0sc1 (LLC-point,
// 16 MiB/step aggregate -> the ~1.8 TB/s wall of r6-r8) to sc0 (L1-bypass,
// L2-CACHEABLE): first reader on an XCD misses to LLC, the other ~31 blocks
// HIT the XCD L2 -> LLC bulk traffic drops ~8x; the 64-reader amplification
// is served by the 8 L2s (~34 TB/s aggregate). Producer h stores remain
// agent-scope write-through (land at LLC pre-flag, no L2 allocation).
// If ws_size can't fit the 64 MiB buffer, fall back to the r8 kernel
// (template<false>: 2-slot + sc0sc1) -- bit-identical to the 2349 us version.

typedef _Float16 half8  __attribute__((ext_vector_type(8)));
typedef float   floatx4 __attribute__((ext_vector_type(4)));

__device__ __forceinline__ float sigf(float x) {
  x = fminf(fmaxf(x, -30.f), 30.f);
  return 1.f / (1.f + __expf(-x));
}
__device__ __forceinline__ float tanhf_fast(float x) {
  x = fminf(fmaxf(x, -15.f), 15.f);
  float e = __expf(2.f * x);
  return (e - 1.f) / (e + 1.f);
}
__device__ __forceinline__ unsigned short f2h(float x) {
  _Float16 h = (_Float16)x;
  return __builtin_bit_cast(unsigned short, h);
}
// agent-scope write-through h store: at LLC once vmcnt(0) drains
__device__ __forceinline__ void store_h(unsigned short* p, float x) {
  __hip_atomic_store(p, f2h(x), __ATOMIC_RELAXED, __HIP_MEMORY_SCOPE_AGENT);
}

// 16B A-load. CACHED: sc0 = L1-bypass, L2-cacheable (safe: addresses are
// never reused across steps). !CACHED: sc0 sc1 = LLC-point read (r8 path).
template <bool CACHED, int IMM>
__device__ __forceinline__ void ld16(half8& dst, const unsigned short* base) {
  if constexpr (CACHED)
    asm volatile("global_load_dwordx4 %0, %1, off offset:%2 sc0"
                 : "=&v"(dst) : "v"(base), "n"(IMM) : "memory");
  else
    asm volatile("global_load_dwordx4 %0, %1, off offset:%2 sc0 sc1"
                 : "=&v"(dst) : "v"(base), "n"(IMM) : "memory");
}

// One pipeline stage: wait pair kc (counted vmcnt), 2*NT MFMAs, reissue slot.
// 16-pair ring = 32 loads in flight (1 wave/CU). B tiles nt<NGATE from LDS
// (swizzled); nt>=NGATE from fcb registers. The "+v" ties make the MFMAs
// data-depend on the wait (rule #18).
#define KSTEP(kc, WN)                                                      \
  {                                                                        \
    asm volatile("s_waitcnt vmcnt(%2)"                                     \
                 : "+v"(ap0[(kc) & 15]), "+v"(ap1[(kc) & 15]) : "n"(WN));  \
    half8 a0 = ap0[(kc) & 15], a1 = ap1[(kc) & 15];                        \
    const int sw = ((kc) * 4 + quad) ^ rsw;                                \
    _Pragma("unroll")                                                      \
    for (int nt = 0; nt < NT; ++nt) {                                      \
      half8 b = (nt < NGATE) ? w8[(nt * 16 + l15) * 128 + sw] : fcb[kc];   \
      acc[0][nt] = __builtin_amdgcn_mfma_f32_16x16x32_f16(a0, b, acc[0][nt], 0, 0, 0); \
      acc[1][nt] = __builtin_amdgcn_mfma_f32_16x16x32_f16(a1, b, acc[1][nt], 0, 0, 0); \
    }                                                                      \
    if ((kc) < 16) {                                                       \
      ld16<CACHED, ((kc) + 16) * 64>(ap0[(kc) & 15], p0);                  \
      ld16<CACHED, ((kc) + 16) * 64>(ap1[(kc) & 15], p1);                  \
    }                                                                      \
  }

// Producer arrival: drain own stores to LLC, then ONE single-writer flag
// store (no RMW, no shared-line contention).
__device__ __forceinline__ void publish(unsigned* qf, int sl, unsigned v, int lane) {
  asm volatile("s_waitcnt vmcnt(0)" ::: "memory");   // h stores at LLC
  if (lane == 0)
    __hip_atomic_store(qf + sl, v, __ATOMIC_RELAXED, __HIP_MEMORY_SCOPE_AGENT);
}
// Consumer wait: wave-wide poll of the quarter's 64 flags (lane i reads
// flag[i]). The compiler-inserted vmcnt(0) before using v also drains our
// own flag store -> the gemm's counted vmcnt ring starts from 0 outstanding.
__device__ __forceinline__ void waitq(const unsigned* qf, unsigned tgt, int lane) {
  for (;;) {
    unsigned v = __hip_atomic_load(qf + lane, __ATOMIC_RELAXED, __HIP_MEMORY_SCOPE_AGENT);
    if (__all(v >= tgt)) break;
    __builtin_amdgcn_s_sleep(1);
  }
}

// gates0 = z @ w_ih^T + b_ih + b_hh   (step-0 gates; h0=c0=0, x=0 for t>=1)
__global__ void prep_gates0(const float* __restrict__ z, const float* __restrict__ w_ih,
                            const float* __restrict__ b_ih, const float* __restrict__ b_hh,
                            float* __restrict__ g0) {
  int j = blockIdx.x;     // 0..4095
  int b = threadIdx.x;    // 0..127
  const float* zr = z + b * LL;
  const float* wr = w_ih + (size_t)j * LL;
  float s = 0.f;
#pragma unroll 4
  for (int k = 0; k < LL; ++k) s += zr[k] * wr[k];
  g0[(size_t)b * G4 + j] = s + b_ih[j] + b_hh[j];
}

// Convert w_hh to fp16 in the persistent kernel's LDS layout.
// Weight slice sl owns units u = sl*16 .. sl*16+15; LDS rows (tile*16+nl) for
// tile 0..3 = gates i,g,f,o of unit nl. Each row's 8-elem k-chunks are
// XOR-swizzled by (nl&7) so the wave's B-reads are same-bank-free.
__global__ void prep_weights(const float* __restrict__ w_hh,
                             unsigned short* __restrict__ wbuf) {
  int R = blockIdx.x;                 // 0..4095 gate rows
  int sl = R >> 6, rr = R & 63, tile = rr >> 4, nl = rr & 15;
  int g = (tile == 0) ? 0 : (tile == 1) ? 2 : (tile == 2) ? 1 : 3;  // i,g,f,o
  const float* src = w_hh + (size_t)(g * HH + sl * 16 + nl) * HH;
  int rsw = nl & 7;
  unsigned short* dst = wbuf + (size_t)R * HH;
  for (int k = threadIdx.x; k < HH; k += blockDim.x) {
    int dk = (((k >> 3) ^ rsw) << 3) | (k & 7);
    _Float16 v = (_Float16)src[k];
    dst[dk] = __builtin_bit_cast(unsigned short, v);
  }
}

// One K=1024 MFMA pass: C[2 mtiles x NT ntiles]. A streamed from h slot via
// ld16<CACHED> 16-deep counted-vmcnt ring. B from LDS (gate tiles) and/or
// fcb registers (fc tile).
template <bool CACHED, int NT, int NGATE>
__device__ __forceinline__ void gemmK(const unsigned short* __restrict__ hb,
                                      const half8* __restrict__ w8,
                                      const half8 (&fcb)[32],
                                      int au0, int au1,   // ushort units
                                      int quad, int rsw, int l15,
                                      floatx4 acc[2][NT]) {
  const unsigned short* p0 = hb + au0;
  const unsigned short* p1 = hb + au1;
  half8 ap0[16], ap1[16];
  ld16<CACHED, 0>(ap0[0], p0);     ld16<CACHED, 0>(ap1[0], p1);
  ld16<CACHED, 64>(ap0[1], p0);    ld16<CACHED, 64>(ap1[1], p1);
  ld16<CACHED, 128>(ap0[2], p0);   ld16<CACHED, 128>(ap1[2], p1);
  ld16<CACHED, 192>(ap0[3], p0);   ld16<CACHED, 192>(ap1[3], p1);
  ld16<CACHED, 256>(ap0[4], p0);   ld16<CACHED, 256>(ap1[4], p1);
  ld16<CACHED, 320>(ap0[5], p0);   ld16<CACHED, 320>(ap1[5], p1);
  ld16<CACHED, 384>(ap0[6], p0);   ld16<CACHED, 384>(ap1[6], p1);
  ld16<CACHED, 448>(ap0[7], p0);   ld16<CACHED, 448>(ap1[7], p1);
  ld16<CACHED, 512>(ap0[8], p0);   ld16<CACHED, 512>(ap1[8], p1);
  ld16<CACHED, 576>(ap0[9], p0);   ld16<CACHED, 576>(ap1[9], p1);
  ld16<CACHED, 640>(ap0[10], p0);  ld16<CACHED, 640>(ap1[10], p1);
  ld16<CACHED, 704>(ap0[11], p0);  ld16<CACHED, 704>(ap1[11], p1);
  ld16<CACHED, 768>(ap0[12], p0);  ld16<CACHED, 768>(ap1[12], p1);
  ld16<CACHED, 832>(ap0[13], p0);  ld16<CACHED, 832>(ap1[13], p1);
  ld16<CACHED, 896>(ap0[14], p0);  ld16<CACHED, 896>(ap1[14], p1);
  ld16<CACHED, 960>(ap0[15], p0);  ld16<CACHED, 960>(ap1[15], p1);
  KSTEP(0, 30)  KSTEP(1, 30)  KSTEP(2, 30)  KSTEP(3, 30)
  KSTEP(4, 30)  KSTEP(5, 30)  KSTEP(6, 30)  KSTEP(7, 30)
  KSTEP(8, 30)  KSTEP(9, 30)  KSTEP(10, 30) KSTEP(11, 30)
  KSTEP(12, 30) KSTEP(13, 30) KSTEP(14, 30) KSTEP(15, 30)
  KSTEP(16, 30) KSTEP(17, 28) KSTEP(18, 26) KSTEP(19, 24)
  KSTEP(20, 22) KSTEP(21, 20) KSTEP(22, 18) KSTEP(23, 16)
  KSTEP(24, 14) KSTEP(25, 12) KSTEP(26, 10) KSTEP(27, 8)
  KSTEP(28, 6)  KSTEP(29, 4)  KSTEP(30, 2)  KSTEP(31, 0)
}

template <bool CACHED>
__global__ __launch_bounds__(64, 1) void lstm_persist(
    const float* __restrict__ g0,
    const unsigned short* __restrict__ wbuf,
    const float* __restrict__ b_ih, const float* __restrict__ b_hh,
    const float* __restrict__ W_fc, const float* __restrict__ b_fc,
    float* __restrict__ out,
    unsigned short* __restrict__ hbuf,   // CACHED: [TT][B][H]; else [2][B][H]
    unsigned* __restrict__ ctl) {        // 4 quarters x 1024 flag words
  extern __shared__ __align__(16) unsigned short sW[];
  const int tid  = threadIdx.x;          // 0..63 (one wave)
  const int lane = tid;
  const int quad = lane >> 4;
  const int l15  = lane & 15;
  const int bid  = blockIdx.x;
  const int sl   = bid >> 2;             // weight slice 0..63
  const int q    = bid & 3;              // batch quarter
  const int mbase = q * 32;
  const int rsw  = l15 & 7;
  const bool carrier = (sl >= CARSL);
  const int pcol = (sl - CARSL) * 16 + l15;   // fc col (carriers only)

  unsigned* qf = ctl + q * 1024;         // this quarter's 64 flags

  { // stage this block's weight slice into LDS (fp16 + swizzled in wbuf)
    const uint4* s4 = (const uint4*)(wbuf + (size_t)sl * 64 * HH);
    uint4* d4 = (uint4*)sW;
    for (int i = tid; i < 64 * HH / 8; i += 64) d4[i] = s4[i];
  }
  __syncthreads();
  const half8* w8 = (const half8*)sW;
  const floatx4 z4 = {0.f, 0.f, 0.f, 0.f};

  // carriers: preload fc B fragments (constant across steps) into registers.
  half8 fcb[32];
  float biasf = 0.f;
  if (carrier) {
    biasf = b_fc[pcol];
    const float* wp = W_fc + (size_t)pcol * HH + quad * 8;
#pragma unroll
    for (int kc = 0; kc < 32; ++kc) {
      float4 f0 = *(const float4*)(wp + kc * 32);
      float4 f1 = *(const float4*)(wp + kc * 32 + 4);
      half8 hv;
      hv[0] = (_Float16)f0.x; hv[1] = (_Float16)f0.y;
      hv[2] = (_Float16)f0.z; hv[3] = (_Float16)f0.w;
      hv[4] = (_Float16)f1.x; hv[5] = (_Float16)f1.y;
      hv[6] = (_Float16)f1.z; hv[7] = (_Float16)f1.w;
      fcb[kc] = hv;
    }
  }

  const int u = sl * 16 + l15;    // hidden unit this lane owns (all 4 gates)
  const float bi = b_ih[u]          + b_hh[u];
  const float bf = b_ih[HH + u]     + b_hh[HH + u];
  const float bg = b_ih[2*HH + u]   + b_hh[2*HH + u];
  const float bo = b_ih[3*HH + u]   + b_hh[3*HH + u];
  float c[2][4] = {{0,0,0,0},{0,0,0,0}};

  // ---- t = 0: gates precomputed in g0; c_prev = 0  (slot 0 both modes)
#pragma unroll
  for (int mt = 0; mt < 2; ++mt)
#pragma unroll
    for (int r = 0; r < 4; ++r) {
      const int m = mbase + mt * 16 + quad * 4 + r;
      const float* gr = g0 + (size_t)m * G4;
      float iv = gr[u], gv = gr[2 * HH + u], ov = gr[3 * HH + u];
      float ct = sigf(iv) * tanhf_fast(gv);
      c[mt][r] = ct;
      store_h(hbuf + (size_t)m * HH + u, sigf(ov) * tanhf_fast(ct));
    }
  publish(qf, sl, 1u, lane);     // h(0) visible -> marker 1

  const int au0 = (mbase +      l15) * HH + quad * 8;  // ushort units
  const int au1 = (mbase + 16 + l15) * HH + quad * 8;

  if (carrier) {
    for (int t = 1; t < TT; ++t) {
      waitq(qf, (unsigned)t, lane);         // quarter peers published h(t-1)
      const unsigned short* hb = hbuf +
          (size_t)(CACHED ? (t - 1) : ((t - 1) & 1)) * BB * HH;
      unsigned short* hw = hbuf + (size_t)(CACHED ? t : (t & 1)) * BB * HH;
      floatx4 acc[2][5] = {{z4, z4, z4, z4, z4}, {z4, z4, z4, z4, z4}};
      gemmK<CACHED, 5, 4>(hb, w8, fcb, au0, au1, quad, rsw, l15, acc);
#pragma unroll
      for (int mt = 0; mt < 2; ++mt)
#pragma unroll
        for (int r = 0; r < 4; ++r) {
          float iv = sigf(acc[mt][0][r] + bi);
          float gv = tanhf_fast(acc[mt][1][r] + bg);
          float fv = sigf(acc[mt][2][r] + bf);
          float ov = sigf(acc[mt][3][r] + bo);
          float ct = fv * c[mt][r] + iv * gv;
          c[mt][r] = ct;
          const int m = mbase + mt * 16 + quad * 4 + r;
          store_h(hw + (size_t)m * HH + u, ov * tanhf_fast(ct));
          out[(size_t)m * (TT * PP) + (size_t)(t - 1) * PP + pcol] =
              acc[mt][4][r] + biasf;
        }
      publish(qf, sl, (unsigned)(t + 1), lane);
    }
    // final fc column: y_{TT-1} = h(TT-1) @ W_fc^T + b_fc
    waitq(qf, (unsigned)TT, lane);
    {
      const unsigned short* hb = hbuf +
          (size_t)(CACHED ? (TT - 1) : ((TT - 1) & 1)) * BB * HH;
      floatx4 acc[2][1] = {{z4}, {z4}};
      gemmK<CACHED, 1, 0>(hb, w8, fcb, au0, au1, quad, rsw, l15, acc);
#pragma unroll
      for (int mt = 0; mt < 2; ++mt)
#pragma unroll
        for (int r = 0; r < 4; ++r) {
          const int m = mbase + mt * 16 + quad * 4 + r;
          out[(size_t)m * (TT * PP) + (size_t)(TT - 1) * PP + pcol] =
              acc[mt][0][r] + biasf;
        }
    }
  } else {
    for (int t = 1; t < TT; ++t) {
      waitq(qf, (unsigned)t, lane);
      const unsigned short* hb = hbuf +
          (size_t)(CACHED ? (t - 1) : ((t - 1) & 1)) * BB * HH;
      unsigned short* hw = hbuf + (size_t)(CACHED ? t : (t & 1)) * BB * HH;
      floatx4 acc[2][4] = {{z4, z4, z4, z4}, {z4, z4, z4, z4}};
      gemmK<CACHED, 4, 4>(hb, w8, fcb, au0, au1, quad, rsw, l15, acc);
#pragma unroll
      for (int mt = 0; mt < 2; ++mt)
#pragma unroll
        for (int r = 0; r < 4; ++r) {
          float iv = sigf(acc[mt][0][r] + bi);
          float gv = tanhf_fast(acc[mt][1][r] + bg);
          float fv = sigf(acc[mt][2][r] + bf);
          float ov = sigf(acc[mt][3][r] + bo);
          float ct = fv * c[mt][r] + iv * gv;
          c[mt][r] = ct;
          const int m = mbase + mt * 16 + quad * 4 + r;
          store_h(hw + (size_t)m * HH + u, ov * tanhf_fast(ct));
        }
      publish(qf, sl, (unsigned)(t + 1), lane);
    }
  }
}

extern "C" void kernel_launch(void* const* d_in, const int* in_sizes, int n_in,
                              void* d_out, int out_size, void* d_ws, size_t ws_size,
                              hipStream_t stream) {
  const float* z    = (const float*)d_in[1];
  const float* w_ih = (const float*)d_in[2];
  const float* w_hh = (const float*)d_in[3];
  const float* b_ih = (const float*)d_in[4];
  const float* b_hh = (const float*)d_in[5];
  const float* W_fc = (const float*)d_in[6];
  const float* b_fc = (const float*)d_in[7];
  float* out = (float*)d_out;

  const size_t ctlB   = 65536;
  const size_t hFull  = (size_t)TT * BB * HH * 2;   // 64 MiB (time-extended)
  const size_t hMin   = (size_t)2  * BB * HH * 2;   // 512 KiB (double buffer)
  const size_t g0B    = (size_t)BB * G4 * 4;        // 2 MiB
  const size_t wbufB  = (size_t)NSL * 64 * HH * 2;  // 8 MiB
  const bool cached = ws_size >= ctlB + hFull + g0B + wbufB;
  const size_t hB = cached ? hFull : hMin;

  char* ws = (char*)d_ws;
  unsigned*       ctl  = (unsigned*)ws;
  unsigned short* hbuf = (unsigned short*)(ws + ctlB);
  float*          g0   = (float*)(ws + ctlB + hB);
  unsigned short* wbuf = (unsigned short*)(ws + ctlB + hB + g0B);

  (void)hipFuncSetAttribute(reinterpret_cast<const void*>(lstm_persist<true>),
                            hipFuncAttributeMaxDynamicSharedMemorySize, 160 * 1024);
  (void)hipFuncSetAttribute(reinterpret_cast<const void*>(lstm_persist<false>),
                            hipFuncAttributeMaxDynamicSharedMemorySize, 160 * 1024);

  hipMemsetAsync(ctl, 0, ctlB, stream);
  prep_gates0 <<<dim3(G4), dim3(BB), 0, stream>>>(z, w_ih, b_ih, b_hh, g0);
  prep_weights<<<dim3(NSL * 64), dim3(256), 0, stream>>>(w_hh, wbuf);
  if (cached)
    lstm_persist<true><<<dim3(NB), dim3(64), 128 * 1024, stream>>>(
        g0, wbuf, b_ih, b_hh, W_fc, b_fc, out, hbuf, ctl);
  else
    lstm_persist<false><<<dim3(NB), dim3(64), 128 * 1024, stream>>>(
        g0, wbuf, b_ih, b_hh, W_fc, b_fc, out, hbuf, ctl);
}

// Round 11
// 2182.090 us; speedup vs baseline: 1.7302x; 1.0677x over previous
//
#include <hip/hip_runtime.h>
#include <stdint.h>

// Problem constants
#define BB   128      // batch
#define LL   128      // latent dim
#define HH   1024     // hidden
#define G4   4096     // 4*H
#define TT   256      // time steps
#define PP   128      // output cols per step

#define NSL  64
#define NB   256
#define CARSL 56                 // slices >= CARSL carry fc work
#define FLS  32                  // flag stride in u32: one 128-B line per flag

// r11: de-serialize the per-step sync chain (r10 showed the floor is latency,
// not bandwidth: LLC-served and L2-served all-gather both run 9.1 us/step).
// (1) one LLC line per flag (stride 32 u32): producer writes a private line;
//     consumer lane i polls line i -> kills the poll-storm write-arbitration
//     on the old shared flag lines.
// (2) carriers publish BEFORE issuing out[] HBM stores: the old order made
//     8/64 producers wait for HBM store acks inside the critical vmcnt(0),
//     making carriers per-step stragglers for the whole quarter. The out
//     stores now drain inside the next waitq's implicit vmcnt(0) (while
//     sleeping anyway), keeping the ring's counted-vmcnt exact.
// (3) poll backoff (2 fast rounds then s_sleep(8)): ~6x less steady storm.

typedef _Float16 half8  __attribute__((ext_vector_type(8)));
typedef float   floatx4 __attribute__((ext_vector_type(4)));

__device__ __forceinline__ float sigf(float x) {
  x = fminf(fmaxf(x, -30.f), 30.f);
  return 1.f / (1.f + __expf(-x));
}
__device__ __forceinline__ float tanhf_fast(float x) {
  x = fminf(fmaxf(x, -15.f), 15.f);
  float e = __expf(2.f * x);
  return (e - 1.f) / (e + 1.f);
}
__device__ __forceinline__ unsigned short f2h(float x) {
  _Float16 h = (_Float16)x;
  return __builtin_bit_cast(unsigned short, h);
}
// agent-scope write-through h store: at LLC once vmcnt(0) drains
__device__ __forceinline__ void store_h(unsigned short* p, float x) {
  __hip_atomic_store(p, f2h(x), __ATOMIC_RELAXED, __HIP_MEMORY_SCOPE_AGENT);
}

// 16B A-load. CACHED: sc0 = L1-bypass, L2-cacheable (safe: h addresses are
// never reused across steps). !CACHED: sc0 sc1 = LLC-point read (r8 path).
template <bool CACHED, int IMM>
__device__ __forceinline__ void ld16(half8& dst, const unsigned short* base) {
  if constexpr (CACHED)
    asm volatile("global_load_dwordx4 %0, %1, off offset:%2 sc0"
                 : "=&v"(dst) : "v"(base), "n"(IMM) : "memory");
  else
    asm volatile("global_load_dwordx4 %0, %1, off offset:%2 sc0 sc1"
                 : "=&v"(dst) : "v"(base), "n"(IMM) : "memory");
}

// One pipeline stage: wait pair kc (counted vmcnt), 2*NT MFMAs, reissue slot.
// 16-pair ring = 32 loads in flight (1 wave/CU). B tiles nt<NGATE from LDS
// (swizzled); nt>=NGATE from fcb registers. The "+v" ties make the MFMAs
// data-depend on the wait (rule #18).
#define KSTEP(kc, WN)                                                      \
  {                                                                        \
    asm volatile("s_waitcnt vmcnt(%2)"                                     \
                 : "+v"(ap0[(kc) & 15]), "+v"(ap1[(kc) & 15]) : "n"(WN));  \
    half8 a0 = ap0[(kc) & 15], a1 = ap1[(kc) & 15];                        \
    const int sw = ((kc) * 4 + quad) ^ rsw;                                \
    _Pragma("unroll")                                                      \
    for (int nt = 0; nt < NT; ++nt) {                                      \
      half8 b = (nt < NGATE) ? w8[(nt * 16 + l15) * 128 + sw] : fcb[kc];   \
      acc[0][nt] = __builtin_amdgcn_mfma_f32_16x16x32_f16(a0, b, acc[0][nt], 0, 0, 0); \
      acc[1][nt] = __builtin_amdgcn_mfma_f32_16x16x32_f16(a1, b, acc[1][nt], 0, 0, 0); \
    }                                                                      \
    if ((kc) < 16) {                                                       \
      ld16<CACHED, ((kc) + 16) * 64>(ap0[(kc) & 15], p0);                  \
      ld16<CACHED, ((kc) + 16) * 64>(ap1[(kc) & 15], p1);                  \
    }                                                                      \
  }

// Producer arrival: drain own h stores to LLC, then ONE single-writer flag
// store to this producer's PRIVATE 128-B line.
__device__ __forceinline__ void publish(unsigned* qf, int sl, unsigned v, int lane) {
  asm volatile("s_waitcnt vmcnt(0)" ::: "memory");   // h stores at LLC
  if (lane == 0)
    __hip_atomic_store(qf + sl * FLS, v, __ATOMIC_RELAXED, __HIP_MEMORY_SCOPE_AGENT);
}
// Consumer wait: lane i polls flag line i (64 distinct LLC lines per quarter).
// 2 fast rounds, then s_sleep(8) backoff. The atomic load's implicit vmcnt(0)
// also drains any deferred out[] stores from the previous epilogue.
__device__ __forceinline__ void waitq(const unsigned* qf, unsigned tgt, int lane) {
  const unsigned* p = qf + lane * FLS;
  int rounds = 0;
  for (;;) {
    unsigned v = __hip_atomic_load(p, __ATOMIC_RELAXED, __HIP_MEMORY_SCOPE_AGENT);
    if (__all(v >= tgt)) break;
    if (rounds < 2) __builtin_amdgcn_s_sleep(1);
    else            __builtin_amdgcn_s_sleep(8);
    ++rounds;
  }
}

// gates0 = z @ w_ih^T + b_ih + b_hh   (step-0 gates; h0=c0=0, x=0 for t>=1)
__global__ void prep_gates0(const float* __restrict__ z, const float* __restrict__ w_ih,
                            const float* __restrict__ b_ih, const float* __restrict__ b_hh,
                            float* __restrict__ g0) {
  int j = blockIdx.x;     // 0..4095
  int b = threadIdx.x;    // 0..127
  const float* zr = z + b * LL;
  const float* wr = w_ih + (size_t)j * LL;
  float s = 0.f;
#pragma unroll 4
  for (int k = 0; k < LL; ++k) s += zr[k] * wr[k];
  g0[(size_t)b * G4 + j] = s + b_ih[j] + b_hh[j];
}

// Convert w_hh to fp16 in the persistent kernel's LDS layout.
// Weight slice sl owns units u = sl*16 .. sl*16+15; LDS rows (tile*16+nl) for
// tile 0..3 = gates i,g,f,o of unit nl. Each row's 8-elem k-chunks are
// XOR-swizzled by (nl&7) so the wave's B-reads are same-bank-free.
__global__ void prep_weights(const float* __restrict__ w_hh,
                             unsigned short* __restrict__ wbuf) {
  int R = blockIdx.x;                 // 0..4095 gate rows
  int sl = R >> 6, rr = R & 63, tile = rr >> 4, nl = rr & 15;
  int g = (tile == 0) ? 0 : (tile == 1) ? 2 : (tile == 2) ? 1 : 3;  // i,g,f,o
  const float* src = w_hh + (size_t)(g * HH + sl * 16 + nl) * HH;
  int rsw = nl & 7;
  unsigned short* dst = wbuf + (size_t)R * HH;
  for (int k = threadIdx.x; k < HH; k += blockDim.x) {
    int dk = (((k >> 3) ^ rsw) << 3) | (k & 7);
    _Float16 v = (_Float16)src[k];
    dst[dk] = __builtin_bit_cast(unsigned short, v);
  }
}

// One K=1024 MFMA pass: C[2 mtiles x NT ntiles]. A streamed from h slot via
// ld16<CACHED> 16-deep counted-vmcnt ring. B from LDS (gate tiles) and/or
// fcb registers (fc tile).
template <bool CACHED, int NT, int NGATE>
__device__ __forceinline__ void gemmK(const unsigned short* __restrict__ hb,
                                      const half8* __restrict__ w8,
                                      const half8 (&fcb)[32],
                                      int au0, int au1,   // ushort units
                                      int quad, int rsw, int l15,
                                      floatx4 acc[2][NT]) {
  const unsigned short* p0 = hb + au0;
  const unsigned short* p1 = hb + au1;
  half8 ap0[16], ap1[16];
  ld16<CACHED, 0>(ap0[0], p0);     ld16<CACHED, 0>(ap1[0], p1);
  ld16<CACHED, 64>(ap0[1], p0);    ld16<CACHED, 64>(ap1[1], p1);
  ld16<CACHED, 128>(ap0[2], p0);   ld16<CACHED, 128>(ap1[2], p1);
  ld16<CACHED, 192>(ap0[3], p0);   ld16<CACHED, 192>(ap1[3], p1);
  ld16<CACHED, 256>(ap0[4], p0);   ld16<CACHED, 256>(ap1[4], p1);
  ld16<CACHED, 320>(ap0[5], p0);   ld16<CACHED, 320>(ap1[5], p1);
  ld16<CACHED, 384>(ap0[6], p0);   ld16<CACHED, 384>(ap1[6], p1);
  ld16<CACHED, 448>(ap0[7], p0);   ld16<CACHED, 448>(ap1[7], p1);
  ld16<CACHED, 512>(ap0[8], p0);   ld16<CACHED, 512>(ap1[8], p1);
  ld16<CACHED, 576>(ap0[9], p0);   ld16<CACHED, 576>(ap1[9], p1);
  ld16<CACHED, 640>(ap0[10], p0);  ld16<CACHED, 640>(ap1[10], p1);
  ld16<CACHED, 704>(ap0[11], p0);  ld16<CACHED, 704>(ap1[11], p1);
  ld16<CACHED, 768>(ap0[12], p0);  ld16<CACHED, 768>(ap1[12], p1);
  ld16<CACHED, 832>(ap0[13], p0);  ld16<CACHED, 832>(ap1[13], p1);
  ld16<CACHED, 896>(ap0[14], p0);  ld16<CACHED, 896>(ap1[14], p1);
  ld16<CACHED, 960>(ap0[15], p0);  ld16<CACHED, 960>(ap1[15], p1);
  KSTEP(0, 30)  KSTEP(1, 30)  KSTEP(2, 30)  KSTEP(3, 30)
  KSTEP(4, 30)  KSTEP(5, 30)  KSTEP(6, 30)  KSTEP(7, 30)
  KSTEP(8, 30)  KSTEP(9, 30)  KSTEP(10, 30) KSTEP(11, 30)
  KSTEP(12, 30) KSTEP(13, 30) KSTEP(14, 30) KSTEP(15, 30)
  KSTEP(16, 30) KSTEP(17, 28) KSTEP(18, 26) KSTEP(19, 24)
  KSTEP(20, 22) KSTEP(21, 20) KSTEP(22, 18) KSTEP(23, 16)
  KSTEP(24, 14) KSTEP(25, 12) KSTEP(26, 10) KSTEP(27, 8)
  KSTEP(28, 6)  KSTEP(29, 4)  KSTEP(30, 2)  KSTEP(31, 0)
}

template <bool CACHED>
__global__ __launch_bounds__(64, 1) void lstm_persist(
    const float* __restrict__ g0,
    const unsigned short* __restrict__ wbuf,
    const float* __restrict__ b_ih, const float* __restrict__ b_hh,
    const float* __restrict__ W_fc, const float* __restrict__ b_fc,
    float* __restrict__ out,
    unsigned short* __restrict__ hbuf,   // CACHED: [TT][B][H]; else [2][B][H]
    unsigned* __restrict__ ctl) {        // 4 quarters x 64 flags x FLS words
  extern __shared__ __align__(16) unsigned short sW[];
  const int tid  = threadIdx.x;          // 0..63 (one wave)
  const int lane = tid;
  const int quad = lane >> 4;
  const int l15  = lane & 15;
  const int bid  = blockIdx.x;
  const int sl   = bid >> 2;             // weight slice 0..63
  const int q    = bid & 3;              // batch quarter
  const int mbase = q * 32;
  const int rsw  = l15 & 7;
  const bool carrier = (sl >= CARSL);
  const int pcol = (sl - CARSL) * 16 + l15;   // fc col (carriers only)

  unsigned* qf = ctl + q * (64 * FLS);   // this quarter's flag lines

  { // stage this block's weight slice into LDS (fp16 + swizzled in wbuf)
    const uint4* s4 = (const uint4*)(wbuf + (size_t)sl * 64 * HH);
    uint4* d4 = (uint4*)sW;
    for (int i = tid; i < 64 * HH / 8; i += 64) d4[i] = s4[i];
  }
  __syncthreads();
  const half8* w8 = (const half8*)sW;
  const floatx4 z4 = {0.f, 0.f, 0.f, 0.f};

  // carriers: preload fc B fragments (constant across steps) into registers.
  half8 fcb[32];
  float biasf = 0.f;
  if (carrier) {
    biasf = b_fc[pcol];
    const float* wp = W_fc + (size_t)pcol * HH + quad * 8;
#pragma unroll
    for (int kc = 0; kc < 32; ++kc) {
      float4 f0 = *(const float4*)(wp + kc * 32);
      float4 f1 = *(const float4*)(wp + kc * 32 + 4);
      half8 hv;
      hv[0] = (_Float16)f0.x; hv[1] = (_Float16)f0.y;
      hv[2] = (_Float16)f0.z; hv[3] = (_Float16)f0.w;
      hv[4] = (_Float16)f1.x; hv[5] = (_Float16)f1.y;
      hv[6] = (_Float16)f1.z; hv[7] = (_Float16)f1.w;
      fcb[kc] = hv;
    }
  }

  const int u = sl * 16 + l15;    // hidden unit this lane owns (all 4 gates)
  const float bi = b_ih[u]          + b_hh[u];
  const float bf = b_ih[HH + u]     + b_hh[HH + u];
  const float bg = b_ih[2*HH + u]   + b_hh[2*HH + u];
  const float bo = b_ih[3*HH + u]   + b_hh[3*HH + u];
  float c[2][4] = {{0,0,0,0},{0,0,0,0}};

  // ---- t = 0: gates precomputed in g0; c_prev = 0  (slot 0 both modes)
#pragma unroll
  for (int mt = 0; mt < 2; ++mt)
#pragma unroll
    for (int r = 0; r < 4; ++r) {
      const int m = mbase + mt * 16 + quad * 4 + r;
      const float* gr = g0 + (size_t)m * G4;
      float iv = gr[u], gv = gr[2 * HH + u], ov = gr[3 * HH + u];
      float ct = sigf(iv) * tanhf_fast(gv);
      c[mt][r] = ct;
      store_h(hbuf + (size_t)m * HH + u, sigf(ov) * tanhf_fast(ct));
    }
  publish(qf, sl, 1u, lane);     // h(0) visible -> marker 1

  const int au0 = (mbase +      l15) * HH + quad * 8;  // ushort units
  const int au1 = (mbase + 16 + l15) * HH + quad * 8;

  if (carrier) {
    for (int t = 1; t < TT; ++t) {
      waitq(qf, (unsigned)t, lane);         // quarter peers published h(t-1)
      const unsigned short* hb = hbuf +
          (size_t)(CACHED ? (t - 1) : ((t - 1) & 1)) * BB * HH;
      unsigned short* hw = hbuf + (size_t)(CACHED ? t : (t & 1)) * BB * HH;
      floatx4 acc[2][5] = {{z4, z4, z4, z4, z4}, {z4, z4, z4, z4, z4}};
      gemmK<CACHED, 5, 4>(hb, w8, fcb, au0, au1, quad, rsw, l15, acc);
      // epilogue: h first (publish depends only on h), out[] AFTER publish
      float yv[2][4];
#pragma unroll
      for (int mt = 0; mt < 2; ++mt)
#pragma unroll
        for (int r = 0; r < 4; ++r) {
          float iv = sigf(acc[mt][0][r] + bi);
          float gv = tanhf_fast(acc[mt][1][r] + bg);
          float fv = sigf(acc[mt][2][r] + bf);
          float ov = sigf(acc[mt][3][r] + bo);
          float ct = fv * c[mt][r] + iv * gv;
          c[mt][r] = ct;
          const int m = mbase + mt * 16 + quad * 4 + r;
          store_h(hw + (size_t)m * HH + u, ov * tanhf_fast(ct));
          yv[mt][r] = acc[mt][4][r] + biasf;
        }
      publish(qf, sl, (unsigned)(t + 1), lane);   // drains ONLY the 8 h stores
#pragma unroll
      for (int mt = 0; mt < 2; ++mt)
#pragma unroll
        for (int r = 0; r < 4; ++r) {
          const int m = mbase + mt * 16 + quad * 4 + r;
          out[(size_t)m * (TT * PP) + (size_t)(t - 1) * PP + pcol] = yv[mt][r];
        }
      // out stores drain inside the next waitq's implicit vmcnt(0)
    }
    // final fc column: y_{TT-1} = h(TT-1) @ W_fc^T + b_fc
    waitq(qf, (unsigned)TT, lane);
    {
      const unsigned short* hb = hbuf +
          (size_t)(CACHED ? (TT - 1) : ((TT - 1) & 1)) * BB * HH;
      floatx4 acc[2][1] = {{z4}, {z4}};
      gemmK<CACHED, 1, 0>(hb, w8, fcb, au0, au1, quad, rsw, l15, acc);
#pragma unroll
      for (int mt = 0; mt < 2; ++mt)
#pragma unroll
        for (int r = 0; r < 4; ++r) {
          const int m = mbase + mt * 16 + quad * 4 + r;
          out[(size_t)m * (TT * PP) + (size_t)(TT - 1) * PP + pcol] =
              acc[mt][0][r] + biasf;
        }
    }
  } else {
    for (int t = 1; t < TT; ++t) {
      waitq(qf, (unsigned)t, lane);
      const unsigned short* hb = hbuf +
          (size_t)(CACHED ? (t - 1) : ((t - 1) & 1)) * BB * HH;
      unsigned short* hw = hbuf + (size_t)(CACHED ? t : (t & 1)) * BB * HH;
      floatx4 acc[2][4] = {{z4, z4, z4, z4}, {z4, z4, z4, z4}};
      gemmK<CACHED, 4, 4>(hb, w8, fcb, au0, au1, quad, rsw, l15, acc);
#pragma unroll
      for (int mt = 0; mt < 2; ++mt)
#pragma unroll
        for (int r = 0; r < 4; ++r) {
          float iv = sigf(acc[mt][0][r] + bi);
          float gv = tanhf_fast(acc[mt][1][r] + bg);
          float fv = sigf(acc[mt][2][r] + bf);
          float ov = sigf(acc[mt][3][r] + bo);
          float ct = fv * c[mt][r] + iv * gv;
          c[mt][r] = ct;
          const int m = mbase + mt * 16 + quad * 4 + r;
          store_h(hw + (size_t)m * HH + u, ov * tanhf_fast(ct));
        }
      publish(qf, sl, (unsigned)(t + 1), lane);
    }
  }
}

extern "C" void kernel_launch(void* const* d_in, const int* in_sizes, int n_in,
                              void* d_out, int out_size, void* d_ws, size_t ws_size,
                              hipStream_t stream) {
  const float* z    = (const float*)d_in[1];
  const float* w_ih = (const float*)d_in[2];
  const float* w_hh = (const float*)d_in[3];
  const float* b_ih = (const float*)d_in[4];
  const float* b_hh = (const float*)d_in[5];
  const float* W_fc = (const float*)d_in[6];
  const float* b_fc = (const float*)d_in[7];
  float* out = (float*)d_out;

  const size_t ctlB   = 65536;                      // 4q x 64 flags x 128 B = 32 KiB used
  const size_t hFull  = (size_t)TT * BB * HH * 2;   // 64 MiB (time-extended)
  const size_t hMin   = (size_t)2  * BB * HH * 2;   // 512 KiB (double buffer)
  const size_t g0B    = (size_t)BB * G4 * 4;        // 2 MiB
  const size_t wbufB  = (size_t)NSL * 64 * HH * 2;  // 8 MiB
  const bool cached = ws_size >= ctlB + hFull + g0B + wbufB;
  const size_t hB = cached ? hFull : hMin;

  char* ws = (char*)d_ws;
  unsigned*       ctl  = (unsigned*)ws;
  unsigned short* hbuf = (unsigned short*)(ws + ctlB);
  float*          g0   = (float*)(ws + ctlB + hB);
  unsigned short* wbuf = (unsigned short*)(ws + ctlB + hB + g0B);

  (void)hipFuncSetAttribute(reinterpret_cast<const void*>(lstm_persist<true>),
                            hipFuncAttributeMaxDynamicSharedMemorySize, 160 * 1024);
  (void)hipFuncSetAttribute(reinterpret_cast<const void*>(lstm_persist<false>),
                            hipFuncAttributeMaxDynamicSharedMemorySize, 160 * 1024);

  hipMemsetAsync(ctl, 0, ctlB, stream);
  prep_gates0 <<<dim3(G4), dim3(BB), 0, stream>>>(z, w_ih, b_ih, b_hh, g0);
  prep_weights<<<dim3(NSL * 64), dim3(256), 0, stream>>>(w_hh, wbuf);
  if (cached)
    lstm_persist<true><<<dim3(NB), dim3(64), 128 * 1024, stream>>>(
        g0, wbuf, b_ih, b_hh, W_fc, b_fc, out, hbuf, ctl);
  else
    lstm_persist<false><<<dim3(NB), dim3(64), 128 * 1024, stream>>>(
        g0, wbuf, b_ih, b_hh, W_fc, b_fc, out, hbuf, ctl);
}

// Round 12
// 2162.245 us; speedup vs baseline: 1.7460x; 1.0092x over previous
//
#include <hip/hip_runtime.h>
#include <stdint.h>

// Problem constants
#define BB   128      // batch
#define LL   128      // latent dim
#define HH   1024     // hidden
#define G4   4096     // 4*H
#define TT   256      // time steps
#define PP   128      // output cols per step

#define NSL  64
#define NB   256
#define CARSL 56                 // slices >= CARSL carry fc work
#define FLS  32                  // flag stride in u32: one 128-B line per flag
#define HROW 2048                // h row stride (ushorts), [1024..2047] mirrors [0..1023]

// r12: dissolve the per-step quarter barrier into pipelined per-group waits.
// Flag group g = slices g*16..g*16+15 produces exactly k-chunks g*8..g*8+7.
// Each block rotates its K-sweep to start at its OWN group (duplicated h rows
// keep load offsets compile-time, r5 infra), waits only for groups g0,g0+1
// up front, and checks prefetched g0+2/g0+3 flag values mid-gemm just before
// those groups' loads issue. Straggler coupling: max-of-64 -> max-of-16, and
// late groups' skew + detect latency hide under ~24 KSTEPs of MFMA. Blocks
// self-pipeline across steps (skew <= 1 step; h(t+1) stores happen only after
// observing ALL flags >= t+1, so h(t-1) readers are always done first).

typedef _Float16 half8  __attribute__((ext_vector_type(8)));
typedef float   floatx4 __attribute__((ext_vector_type(4)));

__device__ __forceinline__ float sigf(float x) {
  x = fminf(fmaxf(x, -30.f), 30.f);
  return 1.f / (1.f + __expf(-x));
}
__device__ __forceinline__ float tanhf_fast(float x) {
  x = fminf(fmaxf(x, -15.f), 15.f);
  float e = __expf(2.f * x);
  return (e - 1.f) / (e + 1.f);
}
__device__ __forceinline__ unsigned short f2h(float x) {
  _Float16 h = (_Float16)x;
  return __builtin_bit_cast(unsigned short, h);
}
// agent-scope write-through h store: at LLC once vmcnt(0) drains
__device__ __forceinline__ void store_h(unsigned short* p, float x) {
  __hip_atomic_store(p, f2h(x), __ATOMIC_RELAXED, __HIP_MEMORY_SCOPE_AGENT);
}

// LLC-point 16B A-load (sc0 sc1): reads where write-through h stores land.
template <int IMM>
__device__ __forceinline__ void ld16(half8& dst, const unsigned short* base) {
  asm volatile("global_load_dwordx4 %0, %1, off offset:%2 sc0 sc1"
               : "=&v"(dst) : "v"(base), "n"(IMM) : "memory");
}
// flag prefetch load (value checked later, mid-gemm)
#define FLD(dst, ptr)                                                      \
  asm volatile("global_load_dword %0, %1, off sc0 sc1"                     \
               : "=&v"(dst) : "v"(ptr) : "memory")

// Producer arrival: drain own h stores to LLC, then ONE single-writer flag
// store to this producer's private 128-B line.
__device__ __forceinline__ void publish(unsigned* qf, int sl, unsigned v, int lane) {
  asm volatile("s_waitcnt vmcnt(0)" ::: "memory");   // h stores at LLC
  if (lane == 0)
    __hip_atomic_store(qf + sl * FLS, v, __ATOMIC_RELAXED, __HIP_MEMORY_SCOPE_AGENT);
}
// Wait for sweep-groups 0 and 1 (32 flags): lanes 0-31 cover group g0,
// lanes 32-63 cover group g0+1. Poll's implicit vmcnt(0) also drains any
// deferred out[] stores from the previous epilogue.
__device__ __forceinline__ void wait01(const unsigned* qf, int g0q, unsigned tgt, int lane) {
  const int idx = ((g0q + (lane >> 5)) & 3) * 16 + (lane & 15);
  const unsigned* p = qf + idx * FLS;
  int rounds = 0;
  for (;;) {
    unsigned v = __hip_atomic_load(p, __ATOMIC_RELAXED, __HIP_MEMORY_SCOPE_AGENT);
    if (__all(v >= tgt)) break;
    if (rounds < 2) __builtin_amdgcn_s_sleep(1);
    else            __builtin_amdgcn_s_sleep(8);
    ++rounds;
  }
}
// Slow-path wait for sweep-group s (16 flags, all lanes via lane&15). Rare.
// Over-draining vmcnt here is safe: ring data already landed in registers.
__device__ __forceinline__ void waitg(const unsigned* qf, int g0q, int s,
                                      unsigned tgt, int lane) {
  const int idx = ((g0q + s) & 3) * 16 + (lane & 15);
  const unsigned* p = qf + idx * FLS;
  for (;;) {
    unsigned v = __hip_atomic_load(p, __ATOMIC_RELAXED, __HIP_MEMORY_SCOPE_AGENT);
    if (__all(v >= tgt)) break;
    __builtin_amdgcn_s_sleep(1);
  }
}
// Full wait over all 64 flags (final fc pass only).
__device__ __forceinline__ void waitq(const unsigned* qf, unsigned tgt, int lane) {
  const unsigned* p = qf + lane * FLS;
  for (;;) {
    unsigned v = __hip_atomic_load(p, __ATOMIC_RELAXED, __HIP_MEMORY_SCOPE_AGENT);
    if (__all(v >= tgt)) break;
    __builtin_amdgcn_s_sleep(1);
  }
}

// gates0 = z @ w_ih^T + b_ih + b_hh   (step-0 gates; h0=c0=0, x=0 for t>=1)
__global__ void prep_gates0(const float* __restrict__ z, const float* __restrict__ w_ih,
                            const float* __restrict__ b_ih, const float* __restrict__ b_hh,
                            float* __restrict__ g0) {
  int j = blockIdx.x;     // 0..4095
  int b = threadIdx.x;    // 0..127
  const float* zr = z + b * LL;
  const float* wr = w_ih + (size_t)j * LL;
  float s = 0.f;
#pragma unroll 4
  for (int k = 0; k < LL; ++k) s += zr[k] * wr[k];
  g0[(size_t)b * G4 + j] = s + b_ih[j] + b_hh[j];
}

// Convert w_hh to fp16 in the persistent kernel's LDS layout (unchanged).
__global__ void prep_weights(const float* __restrict__ w_hh,
                             unsigned short* __restrict__ wbuf) {
  int R = blockIdx.x;                 // 0..4095 gate rows
  int sl = R >> 6, rr = R & 63, tile = rr >> 4, nl = rr & 15;
  int g = (tile == 0) ? 0 : (tile == 1) ? 2 : (tile == 2) ? 1 : 3;  // i,g,f,o
  const float* src = w_hh + (size_t)(g * HH + sl * 16 + nl) * HH;
  int rsw = nl & 7;
  unsigned short* dst = wbuf + (size_t)R * HH;
  for (int k = threadIdx.x; k < HH; k += blockDim.x) {
    int dk = (((k >> 3) ^ rsw) << 3) | (k & 7);
    _Float16 v = (_Float16)src[k];
    dst[dk] = __builtin_bit_cast(unsigned short, v);
  }
}

// MFMA+issue body for sweep chunk j (LDS B index uses rotated physical chunk)
#define KBODY(j)                                                           \
  {                                                                        \
    half8 a0 = ap0[(j) & 15], a1 = ap1[(j) & 15];                          \
    const int sw = (((r0 + (j) * 4) & 127) + quad) ^ rsw;                  \
    _Pragma("unroll")                                                      \
    for (int nt = 0; nt < NT; ++nt) {                                      \
      half8 b = (nt < NGATE) ? w8[(nt * 16 + l15) * 128 + sw] : fcb[j];    \
      acc[0][nt] = __builtin_amdgcn_mfma_f32_16x16x32_f16(a0, b, acc[0][nt], 0, 0, 0); \
      acc[1][nt] = __builtin_amdgcn_mfma_f32_16x16x32_f16(a1, b, acc[1][nt], 0, 0, 0); \
    }                                                                      \
    if ((j) < 16) {                                                        \
      ld16<((j) + 16) * 64>(ap0[(j) & 15], p0);                            \
      ld16<((j) + 16) * 64>(ap1[(j) & 15], p1);                            \
    }                                                                      \
  }
#define KSTEPR(j, WN)                                                      \
  {                                                                        \
    asm volatile("s_waitcnt vmcnt(%2)"                                     \
                 : "+v"(ap0[(j) & 15]), "+v"(ap1[(j) & 15]) : "n"(WN));    \
    KBODY(j)                                                               \
  }

// One K=1024 MFMA pass with rotated sweep + pipelined group dependencies.
// Entry condition: groups g0,g0+1 flags >= tgt (caller ran wait01) and
// vmcnt outstanding == 0.
template <int NT, int NGATE>
__device__ __forceinline__ void gemmP(const unsigned short* __restrict__ hb,
                                      const half8* __restrict__ w8,
                                      const half8 (&fcb)[32],
                                      int au0, int au1, int quad, int rsw,
                                      int l15, int r0, int g0q,
                                      const unsigned* qf, unsigned tgt, int lane,
                                      floatx4 acc[2][NT]) {
  const unsigned short* p0 = hb + au0;
  const unsigned short* p1 = hb + au1;
  // prefetch group-2/3 flag values (oldest vmcnt entries; drained at KSTEP 0)
  unsigned fv2, fv3;
  {
    const unsigned* f2p = qf + (((g0q + 2) & 3) * 16 + (lane & 15)) * FLS;
    const unsigned* f3p = qf + (((g0q + 3) & 3) * 16 + (lane & 15)) * FLS;
    FLD(fv2, f2p);
    FLD(fv3, f3p);
  }
  half8 ap0[16], ap1[16];
  // prologue: sweep chunks 0..15 (groups g0, g0+1 only — already published)
  ld16<0>(ap0[0], p0);     ld16<0>(ap1[0], p1);
  ld16<64>(ap0[1], p0);    ld16<64>(ap1[1], p1);
  ld16<128>(ap0[2], p0);   ld16<128>(ap1[2], p1);
  ld16<192>(ap0[3], p0);   ld16<192>(ap1[3], p1);
  ld16<256>(ap0[4], p0);   ld16<256>(ap1[4], p1);
  ld16<320>(ap0[5], p0);   ld16<320>(ap1[5], p1);
  ld16<384>(ap0[6], p0);   ld16<384>(ap1[6], p1);
  ld16<448>(ap0[7], p0);   ld16<448>(ap1[7], p1);
  ld16<512>(ap0[8], p0);   ld16<512>(ap1[8], p1);
  ld16<576>(ap0[9], p0);   ld16<576>(ap1[9], p1);
  ld16<640>(ap0[10], p0);  ld16<640>(ap1[10], p1);
  ld16<704>(ap0[11], p0);  ld16<704>(ap1[11], p1);
  ld16<768>(ap0[12], p0);  ld16<768>(ap1[12], p1);
  ld16<832>(ap0[13], p0);  ld16<832>(ap1[13], p1);
  ld16<896>(ap0[14], p0);  ld16<896>(ap1[14], p1);
  ld16<960>(ap0[15], p0);  ld16<960>(ap1[15], p1);
  // j=0: vmcnt(30) drains {fv2, fv3, pair 0}; check group 2 before issuing
  // its loads (pairs 16..23 issue during j=0..7)
  asm volatile("s_waitcnt vmcnt(30)"
               : "+v"(ap0[0]), "+v"(ap1[0]), "+v"(fv2), "+v"(fv3));
  if (!__all(fv2 >= tgt)) waitg(qf, g0q, 2, tgt, lane);
  KBODY(0)
  KSTEPR(1, 30)  KSTEPR(2, 30)  KSTEPR(3, 30)
  KSTEPR(4, 30)  KSTEPR(5, 30)  KSTEPR(6, 30)  KSTEPR(7, 30)
  // j=8: check group 3 before issuing its loads (pairs 24..31)
  asm volatile("s_waitcnt vmcnt(30)" : "+v"(ap0[8]), "+v"(ap1[8]));
  if (!__all(fv3 >= tgt)) waitg(qf, g0q, 3, tgt, lane);
  KBODY(8)
  KSTEPR(9, 30)  KSTEPR(10, 30) KSTEPR(11, 30)
  KSTEPR(12, 30) KSTEPR(13, 30) KSTEPR(14, 30) KSTEPR(15, 30)
  KSTEPR(16, 30) KSTEPR(17, 28) KSTEPR(18, 26) KSTEPR(19, 24)
  KSTEPR(20, 22) KSTEPR(21, 20) KSTEPR(22, 18) KSTEPR(23, 16)
  KSTEPR(24, 14) KSTEPR(25, 12) KSTEPR(26, 10) KSTEPR(27, 8)
  KSTEPR(28, 6)  KSTEPR(29, 4)  KSTEPR(30, 2)  KSTEPR(31, 0)
}

__global__ __launch_bounds__(64, 1) void lstm_persist(
    const float* __restrict__ g0,
    const unsigned short* __restrict__ wbuf,
    const float* __restrict__ b_ih, const float* __restrict__ b_hh,
    const float* __restrict__ W_fc, const float* __restrict__ b_fc,
    float* __restrict__ out,
    unsigned short* __restrict__ hbuf,   // [2][B][HROW] fp16, rows duplicated
    unsigned* __restrict__ ctl) {        // 4 quarters x 64 flags x FLS words
  extern __shared__ __align__(16) unsigned short sW[];
  const int tid  = threadIdx.x;          // 0..63 (one wave)
  const int lane = tid;
  const int quad = lane >> 4;
  const int l15  = lane & 15;
  const int bid  = blockIdx.x;
  const int sl   = bid >> 2;             // weight slice 0..63
  const int q    = bid & 3;              // batch quarter
  const int mbase = q * 32;
  const int rsw  = l15 & 7;
  const int g0q  = sl >> 4;              // own flag group 0..3
  const int r0   = g0q * 32;             // LDS chunk rotation (half8 units)
  const bool carrier = (sl >= CARSL);
  const int pcol = (sl - CARSL) * 16 + l15;   // fc col (carriers only)

  unsigned* qf = ctl + q * (64 * FLS);   // this quarter's flag lines

  { // stage this block's weight slice into LDS (fp16 + swizzled in wbuf)
    const uint4* s4 = (const uint4*)(wbuf + (size_t)sl * 64 * HH);
    uint4* d4 = (uint4*)sW;
    for (int i = tid; i < 64 * HH / 8; i += 64) d4[i] = s4[i];
  }
  __syncthreads();
  const half8* w8 = (const half8*)sW;
  const floatx4 z4 = {0.f, 0.f, 0.f, 0.f};

  // carriers: preload fc B fragments IN SWEEP ORDER (rotation folded in so
  // runtime indices never touch the register array — rule #20).
  half8 fcb[32];
  float biasf = 0.f;
  if (carrier) {
    biasf = b_fc[pcol];
    const float* wp = W_fc + (size_t)pcol * HH + quad * 8;
#pragma unroll
    for (int j = 0; j < 32; ++j) {
      const int phys = (g0q * 8 + j) & 31;
      float4 f0 = *(const float4*)(wp + phys * 32);
      float4 f1 = *(const float4*)(wp + phys * 32 + 4);
      half8 hv;
      hv[0] = (_Float16)f0.x; hv[1] = (_Float16)f0.y;
      hv[2] = (_Float16)f0.z; hv[3] = (_Float16)f0.w;
      hv[4] = (_Float16)f1.x; hv[5] = (_Float16)f1.y;
      hv[6] = (_Float16)f1.z; hv[7] = (_Float16)f1.w;
      fcb[j] = hv;
    }
  }

  const int u = sl * 16 + l15;    // hidden unit this lane owns (all 4 gates)
  const float bi = b_ih[u]          + b_hh[u];
  const float bf = b_ih[HH + u]     + b_hh[HH + u];
  const float bg = b_ih[2*HH + u]   + b_hh[2*HH + u];
  const float bo = b_ih[3*HH + u]   + b_hh[3*HH + u];
  float c[2][4] = {{0,0,0,0},{0,0,0,0}};

  // ---- t = 0: gates precomputed in g0; c_prev = 0 (slot 0, duplicated rows)
#pragma unroll
  for (int mt = 0; mt < 2; ++mt)
#pragma unroll
    for (int r = 0; r < 4; ++r) {
      const int m = mbase + mt * 16 + quad * 4 + r;
      const float* gr = g0 + (size_t)m * G4;
      float iv = gr[u], gv = gr[2 * HH + u], ov = gr[3 * HH + u];
      float ct = sigf(iv) * tanhf_fast(gv);
      c[mt][r] = ct;
      float hv = sigf(ov) * tanhf_fast(ct);
      store_h(hbuf + (size_t)m * HROW + u, hv);
      store_h(hbuf + (size_t)m * HROW + 1024 + u, hv);   // mirror
    }
  publish(qf, sl, 1u, lane);     // h(0) visible -> marker 1

  // A-stream bases: rotated start (own group's chunks first), dup rows make
  // all 32 sweep offsets compile-time without wraparound.
  const int au0 = (mbase +      l15) * HROW + g0q * 256 + quad * 8;
  const int au1 = (mbase + 16 + l15) * HROW + g0q * 256 + quad * 8;

  if (carrier) {
    for (int t = 1; t < TT; ++t) {
      wait01(qf, g0q, (unsigned)t, lane);   // own + next group only
      const unsigned short* hb = hbuf + (size_t)((t - 1) & 1) * BB * HROW;
      unsigned short* hw = hbuf + (size_t)(t & 1) * BB * HROW;
      floatx4 acc[2][5] = {{z4, z4, z4, z4, z4}, {z4, z4, z4, z4, z4}};
      gemmP<5, 4>(hb, w8, fcb, au0, au1, quad, rsw, l15, r0, g0q, qf,
                  (unsigned)t, lane, acc);
      float yv[2][4];
#pragma unroll
      for (int mt = 0; mt < 2; ++mt)
#pragma unroll
        for (int r = 0; r < 4; ++r) {
          float iv = sigf(acc[mt][0][r] + bi);
          float gv = tanhf_fast(acc[mt][1][r] + bg);
          float fv = sigf(acc[mt][2][r] + bf);
          float ov = sigf(acc[mt][3][r] + bo);
          float ct = fv * c[mt][r] + iv * gv;
          c[mt][r] = ct;
          const int m = mbase + mt * 16 + quad * 4 + r;
          float hv = ov * tanhf_fast(ct);
          store_h(hw + (size_t)m * HROW + u, hv);
          store_h(hw + (size_t)m * HROW + 1024 + u, hv);
          yv[mt][r] = acc[mt][4][r] + biasf;
        }
      publish(qf, sl, (unsigned)(t + 1), lane);   // drains only the h stores
#pragma unroll
      for (int mt = 0; mt < 2; ++mt)
#pragma unroll
        for (int r = 0; r < 4; ++r) {
          const int m = mbase + mt * 16 + quad * 4 + r;
          out[(size_t)m * (TT * PP) + (size_t)(t - 1) * PP + pcol] = yv[mt][r];
        }
      // out stores drain inside next wait01's implicit vmcnt(0)
    }
    // final fc column: y_{TT-1} = h(TT-1) @ W_fc^T + b_fc
    waitq(qf, (unsigned)TT, lane);
    {
      const unsigned short* hb = hbuf + (size_t)((TT - 1) & 1) * BB * HROW;
      floatx4 acc[2][1] = {{z4}, {z4}};
      gemmP<1, 0>(hb, w8, fcb, au0, au1, quad, rsw, l15, r0, g0q, qf,
                  (unsigned)TT, lane, acc);
#pragma unroll
      for (int mt = 0; mt < 2; ++mt)
#pragma unroll
        for (int r = 0; r < 4; ++r) {
          const int m = mbase + mt * 16 + quad * 4 + r;
          out[(size_t)m * (TT * PP) + (size_t)(TT - 1) * PP + pcol] =
              acc[mt][0][r] + biasf;
        }
    }
  } else {
    for (int t = 1; t < TT; ++t) {
      wait01(qf, g0q, (unsigned)t, lane);
      const unsigned short* hb = hbuf + (size_t)((t - 1) & 1) * BB * HROW;
      unsigned short* hw = hbuf + (size_t)(t & 1) * BB * HROW;
      floatx4 acc[2][4] = {{z4, z4, z4, z4}, {z4, z4, z4, z4}};
      gemmP<4, 4>(hb, w8, fcb, au0, au1, quad, rsw, l15, r0, g0q, qf,
                  (unsigned)t, lane, acc);
#pragma unroll
      for (int mt = 0; mt < 2; ++mt)
#pragma unroll
        for (int r = 0; r < 4; ++r) {
          float iv = sigf(acc[mt][0][r] + bi);
          float gv = tanhf_fast(acc[mt][1][r] + bg);
          float fv = sigf(acc[mt][2][r] + bf);
          float ov = sigf(acc[mt][3][r] + bo);
          float ct = fv * c[mt][r] + iv * gv;
          c[mt][r] = ct;
          const int m = mbase + mt * 16 + quad * 4 + r;
          float hv = ov * tanhf_fast(ct);
          store_h(hw + (size_t)m * HROW + u, hv);
          store_h(hw + (size_t)m * HROW + 1024 + u, hv);
        }
      publish(qf, sl, (unsigned)(t + 1), lane);
    }
  }
}

extern "C" void kernel_launch(void* const* d_in, const int* in_sizes, int n_in,
                              void* d_out, int out_size, void* d_ws, size_t ws_size,
                              hipStream_t stream) {
  const float* z    = (const float*)d_in[1];
  const float* w_ih = (const float*)d_in[2];
  const float* w_hh = (const float*)d_in[3];
  const float* b_ih = (const float*)d_in[4];
  const float* b_hh = (const float*)d_in[5];
  const float* W_fc = (const float*)d_in[6];
  const float* b_fc = (const float*)d_in[7];
  float* out = (float*)d_out;

  // workspace: ctl 64K | hbuf 1M (dup rows) | g0 2M | wbuf 8M  (~11 MiB)
  const size_t ctlB  = 65536;
  const size_t hB    = (size_t)2 * BB * HROW * 2;
  const size_t g0B   = (size_t)BB * G4 * 4;
  char* ws = (char*)d_ws;
  unsigned*       ctl  = (unsigned*)ws;
  unsigned short* hbuf = (unsigned short*)(ws + ctlB);
  float*          g0   = (float*)(ws + ctlB + hB);
  unsigned short* wbuf = (unsigned short*)(ws + ctlB + hB + g0B);

  (void)hipFuncSetAttribute(reinterpret_cast<const void*>(lstm_persist),
                            hipFuncAttributeMaxDynamicSharedMemorySize, 160 * 1024);

  hipMemsetAsync(ctl, 0, ctlB, stream);
  prep_gates0 <<<dim3(G4), dim3(BB), 0, stream>>>(z, w_ih, b_ih, b_hh, g0);
  prep_weights<<<dim3(NSL * 64), dim3(256), 0, stream>>>(w_hh, wbuf);
  lstm_persist<<<dim3(NB), dim3(64), 128 * 1024, stream>>>(g0, wbuf, b_ih, b_hh,
                                                           W_fc, b_fc, out, hbuf, ctl);
}